// Round 8
// baseline (714.683 us; speedup 1.0000x reference)
//
#include <hip/hip_runtime.h>
#include <math.h>

typedef __attribute__((ext_vector_type(8))) __bf16 bf16x8;
typedef __attribute__((ext_vector_type(4))) float f32x4;
typedef __attribute__((ext_vector_type(2))) float f32x2;

#define DEV __device__ __forceinline__

typedef __attribute__((address_space(3))) unsigned int lds_u32;
typedef __attribute__((address_space(1))) unsigned int glb_u32;

DEV unsigned short f2bf(float f) {
    unsigned int u = __builtin_bit_cast(unsigned int, f);
    u += 0x7FFFu + ((u >> 16) & 1u);
    return (unsigned short)(u >> 16);
}
DEV float bf2f(unsigned short u) {
    unsigned int v = (unsigned int)u << 16;
    return __builtin_bit_cast(float, v);
}
DEV unsigned int pack2(float a, float b) {
    return (unsigned int)f2bf(a) | ((unsigned int)f2bf(b) << 16);
}
DEV float gelu_exact(float v) {
    return 0.5f * v * (1.0f + erff(v * 0.70710678118654752f));
}
// tanh-form gelu via sigmoid: x * sigmoid(1.595769x + 0.0713548x^3); |err| <= 3e-3
DEV float gelu_fast(float x) {
    float z = 1.5957691216f * x + 0.0713548163f * x * x * x;
    float e = __expf(-z);
    return x * __builtin_amdgcn_rcpf(1.0f + e);
}

// ---------------------------------------------------------------------------
// small prep kernels
// ---------------------------------------------------------------------------
__global__ void cast_bf16_kernel(const float* __restrict__ src,
                                 unsigned short* __restrict__ dst, int n) {
    int i = blockIdx.x * 256 + threadIdx.x;
    if (i < n) dst[i] = f2bf(src[i]);
}

__global__ void cast_fw1_kernel(const float* __restrict__ src,
                                unsigned short* __restrict__ dst) {
    int i = blockIdx.x * 256 + threadIdx.x;
    if (i < 2048 * 512) {
        int row = i >> 9, k = i & 511;
        dst[i] = f2bf(src[row * 514 + k]);
    }
}

__global__ void gb_kernel(const float* __restrict__ x,
                          const float* __restrict__ LW1, const float* __restrict__ Lb1,
                          const float* __restrict__ LW2, const float* __restrict__ Lb2,
                          float* __restrict__ gb) {
    __shared__ float t[8][512];
    const int b0 = blockIdx.x * 8, tid = threadIdx.x;
    for (int idx = tid; idx < 8 * 512; idx += 256) {
        int bb = idx >> 9, j = idx & 511;
        float s0 = x[((size_t)(b0 + bb) * 256 + 128) * 514 + 512];
        float s1 = x[((size_t)(b0 + bb) * 256 + 128) * 514 + 513];
        t[bb][j] = gelu_exact(LW1[j * 2] * s0 + LW1[j * 2 + 1] * s1 + Lb1[j]);
    }
    __syncthreads();
    const int i = tid;
    float a0[8], a1[8];
    float l0 = Lb2[i], l1 = Lb2[i + 256];
    #pragma unroll
    for (int bb = 0; bb < 8; ++bb) { a0[bb] = l0; a1[bb] = l1; }
    for (int j = 0; j < 512; ++j) {
        float w0 = LW2[(size_t)i * 512 + j];
        float w1 = LW2[(size_t)(i + 256) * 512 + j];
        #pragma unroll
        for (int bb = 0; bb < 8; ++bb) {
            a0[bb] += w0 * t[bb][j];
            a1[bb] += w1 * t[bb][j];
        }
    }
    #pragma unroll
    for (int bb = 0; bb < 8; ++bb) {
        gb[(size_t)(b0 + bb) * 512 + i] = a0[bb];
        gb[(size_t)(b0 + bb) * 512 + i + 256] = a1[bb];
    }
}

__global__ void sc_copy_kernel(const float* __restrict__ x, float* __restrict__ out,
                               float* __restrict__ scbuf) {
    size_t idx = (size_t)blockIdx.x * 256 + threadIdx.x;
    size_t off = idx * 514 + 512;
    f32x2 v = *(const f32x2*)(x + off);
    *(f32x2*)(out + off) = v;
    *(f32x2*)(scbuf + idx * 2) = v;
}

// ---------------------------------------------------------------------------
// mixer: unchanged from round 5
// ---------------------------------------------------------------------------
#define MPAD 264

__global__ __launch_bounds__(256, 2) void mixer_kernel(
    const float* __restrict__ x, const float* __restrict__ bs,
    const float* __restrict__ Hb1, const float* __restrict__ Hb2,
    const unsigned short* __restrict__ Wsb,
    const unsigned short* __restrict__ HW1b,
    const unsigned short* __restrict__ HW2b,
    const float* __restrict__ gb,
    float* __restrict__ out,
    unsigned short* __restrict__ Xb) {
    __shared__ __attribute__((aligned(16))) char smem[33792 + 34816];
    unsigned short* XT = (unsigned short*)smem;
    unsigned short* S = (unsigned short*)(smem + 33792);
    unsigned short* ST = S;

    const int bid = blockIdx.x;
    const int b = bid >> 3;
    const int h = bid & 7;
    const int tid = threadIdx.x;
    const int lane = tid & 63;
    const int w = tid >> 6;
    const int l15 = lane & 15;
    const int l4 = lane >> 4;

    {
        const int c = lane;
        const float* xp = x + ((size_t)b * 256) * 514 + (size_t)h * 64 + c;
        for (int i = 0; i < 32; ++i) {
            int p = (i * 4 + w) * 2;
            float v0 = xp[(size_t)p * 514];
            float v1 = xp[(size_t)(p + 1) * 514];
            *(unsigned int*)&XT[c * MPAD + p] = pack2(v0, v1);
        }
    }
    __syncthreads();

    f32x4 acc[4][4];

    #pragma unroll
    for (int mt = 0; mt < 4; ++mt)
        #pragma unroll
        for (int nt = 0; nt < 4; ++nt) acc[mt][nt] = 0.f;
    {
        bf16x8 bnx[4];
        #pragma unroll
        for (int nt = 0; nt < 4; ++nt)
            bnx[nt] = *(const bf16x8*)(Wsb + (size_t)(w * 64 + nt * 16 + l15) * 256 + l4 * 8);
        for (int kc = 0; kc < 8; ++kc) {
            bf16x8 bcur[4];
            #pragma unroll
            for (int nt = 0; nt < 4; ++nt) bcur[nt] = bnx[nt];
            if (kc < 7) {
                #pragma unroll
                for (int nt = 0; nt < 4; ++nt)
                    bnx[nt] = *(const bf16x8*)(Wsb + (size_t)(w * 64 + nt * 16 + l15) * 256 + (kc + 1) * 32 + l4 * 8);
            }
            #pragma unroll
            for (int mt = 0; mt < 4; ++mt) {
                bf16x8 afr = *(const bf16x8*)&XT[(mt * 16 + l15) * MPAD + kc * 32 + l4 * 8];
                #pragma unroll
                for (int nt = 0; nt < 4; ++nt)
                    acc[mt][nt] = __builtin_amdgcn_mfma_f32_16x16x32_bf16(afr, bcur[nt], acc[mt][nt], 0, 0, 0);
            }
        }
    }
    #pragma unroll
    for (int nt = 0; nt < 4; ++nt) {
        int o = w * 64 + nt * 16 + l15;
        float bsv = bs[o];
        float g = gb[(size_t)b * 512 + o];
        float be = gb[(size_t)b * 512 + 256 + o];
        #pragma unroll
        for (int mt = 0; mt < 4; ++mt)
            #pragma unroll
            for (int r = 0; r < 4; ++r) {
                int c = mt * 16 + l4 * 4 + r;
                S[c * MPAD + o] = f2bf((acc[mt][nt][r] + bsv) * g + be);
            }
    }
    __syncthreads();

    const unsigned short* W2p = HW1b + (size_t)h * 65536;
    #pragma unroll
    for (int mt = 0; mt < 4; ++mt)
        #pragma unroll
        for (int nt = 0; nt < 4; ++nt) acc[mt][nt] = 0.f;
    {
        bf16x8 bnx[4];
        #pragma unroll
        for (int nt = 0; nt < 4; ++nt)
            bnx[nt] = *(const bf16x8*)(W2p + (size_t)(w * 64 + nt * 16 + l15) * 256 + l4 * 8);
        for (int kc = 0; kc < 8; ++kc) {
            bf16x8 bcur[4];
            #pragma unroll
            for (int nt = 0; nt < 4; ++nt) bcur[nt] = bnx[nt];
            if (kc < 7) {
                #pragma unroll
                for (int nt = 0; nt < 4; ++nt)
                    bnx[nt] = *(const bf16x8*)(W2p + (size_t)(w * 64 + nt * 16 + l15) * 256 + (kc + 1) * 32 + l4 * 8);
            }
            #pragma unroll
            for (int mt = 0; mt < 4; ++mt) {
                bf16x8 afr = *(const bf16x8*)&S[(mt * 16 + l15) * MPAD + kc * 32 + l4 * 8];
                #pragma unroll
                for (int nt = 0; nt < 4; ++nt)
                    acc[mt][nt] = __builtin_amdgcn_mfma_f32_16x16x32_bf16(afr, bcur[nt], acc[mt][nt], 0, 0, 0);
            }
        }
    }
    #pragma unroll
    for (int nt = 0; nt < 4; ++nt) {
        int kk = w * 64 + nt * 16 + l15;
        float hb = Hb1[(size_t)h * 256 + kk];
        #pragma unroll
        for (int mt = 0; mt < 4; ++mt)
            #pragma unroll
            for (int r = 0; r < 4; ++r) {
                int c = mt * 16 + l4 * 4 + r;
                XT[c * MPAD + kk] = f2bf(gelu_fast(acc[mt][nt][r] + hb));
            }
    }
    __syncthreads();

    const unsigned short* W3p = HW2b + (size_t)h * 65536;
    #pragma unroll
    for (int mt = 0; mt < 4; ++mt)
        #pragma unroll
        for (int nt = 0; nt < 4; ++nt) acc[mt][nt] = 0.f;
    {
        bf16x8 bnx[4];
        #pragma unroll
        for (int nt = 0; nt < 4; ++nt)
            bnx[nt] = *(const bf16x8*)(W3p + (size_t)(w * 64 + nt * 16 + l15) * 256 + l4 * 8);
        for (int kc = 0; kc < 8; ++kc) {
            bf16x8 bcur[4];
            #pragma unroll
            for (int nt = 0; nt < 4; ++nt) bcur[nt] = bnx[nt];
            if (kc < 7) {
                #pragma unroll
                for (int nt = 0; nt < 4; ++nt)
                    bnx[nt] = *(const bf16x8*)(W3p + (size_t)(w * 64 + nt * 16 + l15) * 256 + (kc + 1) * 32 + l4 * 8);
            }
            #pragma unroll
            for (int mt = 0; mt < 4; ++mt) {
                bf16x8 afr = *(const bf16x8*)&XT[(mt * 16 + l15) * MPAD + kc * 32 + l4 * 8];
                #pragma unroll
                for (int nt = 0; nt < 4; ++nt)
                    acc[mt][nt] = __builtin_amdgcn_mfma_f32_16x16x32_bf16(afr, bcur[nt], acc[mt][nt], 0, 0, 0);
            }
        }
    }
    #pragma unroll
    for (int nt = 0; nt < 4; ++nt) {
        int p = w * 64 + nt * 16 + l15;
        float hb = Hb2[(size_t)h * 256 + p];
        #pragma unroll
        for (int mt = 0; mt < 4; ++mt) {
            ushort4 uv;
            uv.x = f2bf(acc[mt][nt][0] + hb);
            uv.y = f2bf(acc[mt][nt][1] + hb);
            uv.z = f2bf(acc[mt][nt][2] + hb);
            uv.w = f2bf(acc[mt][nt][3] + hb);
            *(ushort4*)(ST + p * 68 + mt * 16 + l4 * 4) = uv;
        }
    }
    __syncthreads();

    #pragma unroll
    for (int s = 0; s < 16; ++s) {
        int row = s * 16 + w * 4 + l4;
        ushort4 u = *(const ushort4*)(ST + row * 68 + l15 * 4);
        const float* xr = x + ((size_t)(b * 256 + row)) * 514 + h * 64 + l15 * 4;
        f32x2 xa = *(const f32x2*)xr;
        f32x2 xc = *(const f32x2*)(xr + 2);
        float o0 = bf2f(u.x) + xa.x;
        float o1 = bf2f(u.y) + xa.y;
        float o2 = bf2f(u.z) + xc.x;
        float o3 = bf2f(u.w) + xc.y;
        float* orow = out + ((size_t)(b * 256 + row)) * 514 + h * 64 + l15 * 4;
        f32x2 w0; w0.x = o0; w0.y = o1;
        f32x2 w1; w1.x = o2; w1.y = o3;
        *(f32x2*)orow = w0;
        *(f32x2*)(orow + 2) = w1;
        ushort4 xo;
        xo.x = f2bf(o0); xo.y = f2bf(o1); xo.z = f2bf(o2); xo.w = f2bf(o3);
        *(ushort4*)(Xb + ((size_t)(b * 256 + row)) * 512 + h * 64 + l15 * 4) = xo;
    }
}

// ---------------------------------------------------------------------------
// GEMM v4: 256x256 tile, BK=64, 8 waves as 2M x 4N (wave tile 128x64).
// ONE barrier per K-tile: issue all 8 global_load_lds for t+1, then
// 24 ds_read + 64 MFMA (compiler-interleaved), vmcnt(0), s_barrier.
// LDS 128KB (A 2x32K, B 2x32K).
// ---------------------------------------------------------------------------
DEV void stage_half(const unsigned short* g, size_t gstride, int row0, int k0,
                    char* half_base, int w, int lane) {
    const int slot = lane & 7;
    const int r8 = lane >> 3;
    const int swz = (slot ^ r8) * 16;
    #pragma unroll
    for (int i = 0; i < 2; ++i) {
        int chunk = w * 2 + i;  // 0..15 within half
        int row = chunk * 8 + r8;
        const char* src = (const char*)(g + (size_t)(row0 + row) * gstride + k0) + swz;
        __builtin_amdgcn_global_load_lds((const glb_u32*)src,
                                         (lds_u32*)(half_base + chunk * 1024), 16, 0, 0);
    }
}

DEV void stage4(const unsigned short* A, size_t sA, int m0,
                const unsigned short* B, size_t sB, int n0, int k0,
                char* Abuf, char* Bbuf, int w, int lane) {
    stage_half(A, sA, m0, k0, Abuf, w, lane);
    stage_half(A, sA, m0 + 128, k0, Abuf + 16384, w, lane);
    stage_half(B, sB, n0, k0, Bbuf, w, lane);
    stage_half(B, sB, n0 + 128, k0, Bbuf + 16384, w, lane);
}

DEV void tile_body(const unsigned short* A, size_t sA, int m0,
                   const unsigned short* B, size_t sB, int n0,
                   char* smem, int cb, int kn, bool more,
                   int vA0, int vA1, int vB0, int vB1,
                   int w, int lane, f32x4 (&acc)[8][4]) {
    if (more) {
        int nb = 32768 - cb;
        stage4(A, sA, m0, B, sB, n0, kn, smem + nb, smem + 65536 + nb, w, lane);
    }
    __builtin_amdgcn_s_setprio(1);
    #pragma unroll
    for (int kk = 0; kk < 2; ++kk) {
        const int vA = kk ? vA1 : vA0;
        const int vB = kk ? vB1 : vB0;
        bf16x8 bf[4];
        #pragma unroll
        for (int nf = 0; nf < 4; ++nf)
            bf[nf] = *(const bf16x8*)(smem + vB + cb + nf * 2048);
        #pragma unroll
        for (int mh = 0; mh < 2; ++mh) {
            bf16x8 af[4];
            #pragma unroll
            for (int mf = 0; mf < 4; ++mf)
                af[mf] = *(const bf16x8*)(smem + vA + cb + mh * 8192 + mf * 2048);
            #pragma unroll
            for (int mf = 0; mf < 4; ++mf)
                #pragma unroll
                for (int nf = 0; nf < 4; ++nf)
                    acc[mh * 4 + mf][nf] = __builtin_amdgcn_mfma_f32_16x16x32_bf16(
                        af[mf], bf[nf], acc[mh * 4 + mf][nf], 0, 0, 0);
        }
    }
    __builtin_amdgcn_s_setprio(0);
    if (more) asm volatile("s_waitcnt vmcnt(0)" ::: "memory");
    __builtin_amdgcn_s_barrier();
}

DEV void gemm_loop(const unsigned short* A, size_t sA,
                   const unsigned short* B, size_t sB,
                   int m0, int n0, int NT,
                   char* smem, int w, int lane, f32x4 (&acc)[8][4]) {
    const int wm = w >> 2, wn = w & 3;
    const int l15 = lane & 15, l4 = lane >> 4;
    const int sw = (l15 & 7) << 4;
    const int k0off = (l4 * 16) ^ sw;
    const int k1off = (64 + l4 * 16) ^ sw;
    const int aBase = (wm * 128 + l15) * 128;
    const int bBase = 65536 + (wn * 64 + l15) * 128;
    const int vA0 = aBase + k0off, vA1 = aBase + k1off;
    const int vB0 = bBase + k0off, vB1 = bBase + k1off;

    stage4(A, sA, m0, B, sB, n0, 0, smem, smem + 65536, w, lane);
    asm volatile("s_waitcnt vmcnt(0)" ::: "memory");
    __builtin_amdgcn_s_barrier();

    for (int t = 0; t < NT; t += 2) {
        tile_body(A, sA, m0, B, sB, n0, smem, 0, (t + 1) * 64, t + 1 < NT,
                  vA0, vA1, vB0, vB1, w, lane, acc);
        tile_body(A, sA, m0, B, sB, n0, smem, 32768, (t + 2) * 64, t + 2 < NT,
                  vA0, vA1, vB0, vB1, w, lane, acc);
    }
}

// GEMM1: G = gelu(Xb @ FW1b^T + Fb1 + sc0*w512 + sc1*w513), coalesced via LDS bounce
__global__ __launch_bounds__(512, 1) void gemm1_kernel(
    const unsigned short* __restrict__ A,
    const unsigned short* __restrict__ B,
    const float* __restrict__ Fb1,
    const float* __restrict__ FW1,
    const float* __restrict__ scbuf,
    long pass_m0,
    unsigned short* __restrict__ G) {
    __shared__ __attribute__((aligned(16))) char smem[131072];

    const int nwg = gridDim.x;
    const int cpx = nwg >> 3;
    const int bid = (blockIdx.x & 7) * cpx + (blockIdx.x >> 3);
    const int m0 = (bid >> 3) * 256;
    const int n0 = (bid & 7) * 256;
    const int tid = threadIdx.x;
    const int lane = tid & 63;
    const int w = tid >> 6;
    const int l15 = lane & 15;
    const int l4 = lane >> 4;
    const int wm = w >> 2, wn = w & 3;

    f32x4 acc[8][4];
    #pragma unroll
    for (int mf = 0; mf < 8; ++mf)
        #pragma unroll
        for (int nf = 0; nf < 4; ++nf) acc[mf][nf] = 0.f;

    gemm_loop(A, 512, B, 512, m0, n0, 8, smem, w, lane, acc);

    // epilogue: bias + sc + gelu -> bf16, LDS bounce for coalesced stores.
    // LT pitch = 264 ushorts (528 B): 256 data cols + 8 pad.  (r7 bug: was 136)
    float fb[4], wa[4], wb[4];
    #pragma unroll
    for (int nf = 0; nf < 4; ++nf) {
        int n = n0 + wn * 64 + nf * 16 + l15;
        fb[nf] = Fb1[n];
        wa[nf] = FW1[(size_t)n * 514 + 512];
        wb[nf] = FW1[(size_t)n * 514 + 513];
    }
    unsigned short* LT = (unsigned short*)smem;  // [128][264] (528B pitch)
    #pragma unroll
    for (int ph = 0; ph < 2; ++ph) {
        if (wm == ph) {
            #pragma unroll
            for (int mfg = 0; mfg < 8; ++mfg) {
                f32x2 sc[4];
                #pragma unroll
                for (int r = 0; r < 4; ++r) {
                    long rowg = pass_m0 + m0 + ph * 128 + mfg * 16 + l4 * 4 + r;
                    sc[r] = *(const f32x2*)(scbuf + rowg * 2);
                }
                #pragma unroll
                for (int nf = 0; nf < 4; ++nf)
                    #pragma unroll
                    for (int r = 0; r < 4; ++r) {
                        float v = acc[mfg][nf][r] + fb[nf] + sc[r].x * wa[nf] + sc[r].y * wb[nf];
                        int rl = mfg * 16 + l4 * 4 + r;
                        LT[rl * 264 + wn * 64 + nf * 16 + l15] = f2bf(gelu_fast(v));
                    }
            }
        }
        __syncthreads();
        {
            const int row16 = tid >> 5, col16 = tid & 31;
            #pragma unroll
            for (int sp = 0; sp < 8; ++sp) {
                int row = sp * 16 + row16;
                uint4 d = *(const uint4*)((const char*)smem + row * 528 + col16 * 16);
                *(uint4*)(G + ((size_t)(m0 + ph * 128 + row)) * 2048 + n0 + col16 * 8) = d;
            }
        }
        __syncthreads();
    }
}

// GEMM2: io[., 0..511] += G @ FW2b^T + Fb2
__global__ __launch_bounds__(512, 1) void gemm2_kernel(
    const unsigned short* __restrict__ A,
    const unsigned short* __restrict__ B,
    const float* __restrict__ Fb2,
    long pass_m0,
    float* __restrict__ io) {
    __shared__ __attribute__((aligned(16))) char smem[131072];

    const int nwg = gridDim.x;
    const int cpx = nwg >> 3;
    const int bid = (blockIdx.x & 7) * cpx + (blockIdx.x >> 3);
    const int m0 = (bid >> 1) * 256;
    const int n0 = (bid & 1) * 256;
    const int tid = threadIdx.x;
    const int lane = tid & 63;
    const int w = tid >> 6;
    const int l15 = lane & 15;
    const int l4 = lane >> 4;
    const int wm = w >> 2, wn = w & 3;

    f32x4 acc[8][4];
    #pragma unroll
    for (int mf = 0; mf < 8; ++mf)
        #pragma unroll
        for (int nf = 0; nf < 4; ++nf) acc[mf][nf] = 0.f;

    gemm_loop(A, 2048, B, 2048, m0, n0, 32, smem, w, lane, acc);

    #pragma unroll
    for (int nf = 0; nf < 4; ++nf) {
        int n = n0 + wn * 64 + nf * 16 + l15;
        float fbv = Fb2[n];
        #pragma unroll
        for (int mfg = 0; mfg < 8; ++mfg)
            #pragma unroll
            for (int r = 0; r < 4; ++r) {
                long rowg = pass_m0 + m0 + wm * 128 + mfg * 16 + l4 * 4 + r;
                float* p = io + rowg * 514 + n;
                *p = acc[mfg][nf][r] + fbv + *p;
            }
    }
}

// ---------------------------------------------------------------------------
extern "C" void kernel_launch(void* const* d_in, const int* in_sizes, int n_in,
                              void* d_out, int out_size, void* d_ws, size_t ws_size,
                              hipStream_t stream) {
    const float* x = (const float*)d_in[0];
    const float* Ws = (const float*)d_in[1];
    const float* bs = (const float*)d_in[2];
    const float* LW1 = (const float*)d_in[3];
    const float* Lb1 = (const float*)d_in[4];
    const float* LW2 = (const float*)d_in[5];
    const float* Lb2 = (const float*)d_in[6];
    const float* HW1 = (const float*)d_in[7];
    const float* Hb1 = (const float*)d_in[8];
    const float* HW2 = (const float*)d_in[9];
    const float* Hb2 = (const float*)d_in[10];
    const float* FW1 = (const float*)d_in[11];
    const float* Fb1 = (const float*)d_in[12];
    const float* FW2 = (const float*)d_in[13];
    const float* Fb2 = (const float*)d_in[14];
    float* out = (float*)d_out;

    char* ws = (char*)d_ws;
    unsigned short* Wsb = (unsigned short*)(ws);                 // 131072 B
    unsigned short* HW1b = (unsigned short*)(ws + 131072);       // 1048576 B
    unsigned short* HW2b = (unsigned short*)(ws + 1179648);      // 1048576 B
    unsigned short* FW1b = (unsigned short*)(ws + 2228224);      // 2097152 B
    unsigned short* FW2b = (unsigned short*)(ws + 4325376);      // 2097152 B
    float* gb = (float*)(ws + 6422528);                          // 524288 B
    float* scbuf = (float*)(ws + 6946816);                       // 524288 B
    unsigned short* Xb = (unsigned short*)(ws + 7471104);        // 67108864 B
    unsigned short* Gbuf = (unsigned short*)(ws + 7471104 + 67108864);

    const size_t fixed = 7471104 + 67108864;
    int npass = 32;
    for (int np = 2; np <= 32; np *= 2) {
        if (fixed + (size_t)268435456 / np <= ws_size) { npass = np; break; }
    }
    const long Mtot = 65536;
    const long Mp = Mtot / npass;

    cast_bf16_kernel<<<256, 256, 0, stream>>>(Ws, Wsb, 65536);
    cast_bf16_kernel<<<2048, 256, 0, stream>>>(HW1, HW1b, 524288);
    cast_bf16_kernel<<<2048, 256, 0, stream>>>(HW2, HW2b, 524288);
    cast_bf16_kernel<<<4096, 256, 0, stream>>>(FW2, FW2b, 1048576);
    cast_fw1_kernel<<<4096, 256, 0, stream>>>(FW1, FW1b);
    gb_kernel<<<32, 256, 0, stream>>>(x, LW1, Lb1, LW2, Lb2, gb);
    sc_copy_kernel<<<256, 256, 0, stream>>>(x, out, scbuf);

    mixer_kernel<<<2048, 256, 0, stream>>>(x, bs, Hb1, Hb2, Wsb, HW1b, HW2b, gb, out, Xb);

    for (int p = 0; p < npass; ++p) {
        long m0 = (long)p * Mp;
        gemm1_kernel<<<(int)(Mp / 256) * 8, 512, 0, stream>>>(
            Xb + m0 * 512, FW1b, Fb1, FW1, scbuf, m0, Gbuf);
        gemm2_kernel<<<(int)(Mp / 256) * 2, 512, 0, stream>>>(
            Gbuf, FW2b, Fb2, m0, out);
    }
}

// Round 9
// 665.798 us; speedup vs baseline: 1.0734x; 1.0734x over previous
//
#include <hip/hip_runtime.h>
#include <math.h>

typedef __attribute__((ext_vector_type(8))) __bf16 bf16x8;
typedef __attribute__((ext_vector_type(4))) float f32x4;
typedef __attribute__((ext_vector_type(2))) float f32x2;

#define DEV __device__ __forceinline__

typedef __attribute__((address_space(3))) unsigned int lds_u32;
typedef __attribute__((address_space(1))) unsigned int glb_u32;

DEV unsigned short f2bf(float f) {
    unsigned int u = __builtin_bit_cast(unsigned int, f);
    u += 0x7FFFu + ((u >> 16) & 1u);
    return (unsigned short)(u >> 16);
}
DEV float bf2f(unsigned short u) {
    unsigned int v = (unsigned int)u << 16;
    return __builtin_bit_cast(float, v);
}
DEV unsigned int pack2(float a, float b) {
    return (unsigned int)f2bf(a) | ((unsigned int)f2bf(b) << 16);
}
DEV float gelu_exact(float v) {
    return 0.5f * v * (1.0f + erff(v * 0.70710678118654752f));
}
// tanh-form gelu via sigmoid: x * sigmoid(1.595769x + 0.0713548x^3); |err| <= 3e-3
DEV float gelu_fast(float x) {
    float z = 1.5957691216f * x + 0.0713548163f * x * x * x;
    float e = __expf(-z);
    return x * __builtin_amdgcn_rcpf(1.0f + e);
}

// ---------------------------------------------------------------------------
// small prep kernels
// ---------------------------------------------------------------------------
__global__ void cast_bf16_kernel(const float* __restrict__ src,
                                 unsigned short* __restrict__ dst, int n) {
    int i = blockIdx.x * 256 + threadIdx.x;
    if (i < n) dst[i] = f2bf(src[i]);
}

__global__ void cast_fw1_kernel(const float* __restrict__ src,
                                unsigned short* __restrict__ dst) {
    int i = blockIdx.x * 256 + threadIdx.x;
    if (i < 2048 * 512) {
        int row = i >> 9, k = i & 511;
        dst[i] = f2bf(src[row * 514 + k]);
    }
}

__global__ void gb_kernel(const float* __restrict__ x,
                          const float* __restrict__ LW1, const float* __restrict__ Lb1,
                          const float* __restrict__ LW2, const float* __restrict__ Lb2,
                          float* __restrict__ gb) {
    __shared__ float t[8][512];
    const int b0 = blockIdx.x * 8, tid = threadIdx.x;
    for (int idx = tid; idx < 8 * 512; idx += 256) {
        int bb = idx >> 9, j = idx & 511;
        float s0 = x[((size_t)(b0 + bb) * 256 + 128) * 514 + 512];
        float s1 = x[((size_t)(b0 + bb) * 256 + 128) * 514 + 513];
        t[bb][j] = gelu_exact(LW1[j * 2] * s0 + LW1[j * 2 + 1] * s1 + Lb1[j]);
    }
    __syncthreads();
    const int i = tid;
    float a0[8], a1[8];
    float l0 = Lb2[i], l1 = Lb2[i + 256];
    #pragma unroll
    for (int bb = 0; bb < 8; ++bb) { a0[bb] = l0; a1[bb] = l1; }
    for (int j = 0; j < 512; ++j) {
        float w0 = LW2[(size_t)i * 512 + j];
        float w1 = LW2[(size_t)(i + 256) * 512 + j];
        #pragma unroll
        for (int bb = 0; bb < 8; ++bb) {
            a0[bb] += w0 * t[bb][j];
            a1[bb] += w1 * t[bb][j];
        }
    }
    #pragma unroll
    for (int bb = 0; bb < 8; ++bb) {
        gb[(size_t)(b0 + bb) * 512 + i] = a0[bb];
        gb[(size_t)(b0 + bb) * 512 + i + 256] = a1[bb];
    }
}

__global__ void sc_copy_kernel(const float* __restrict__ x, float* __restrict__ out,
                               float* __restrict__ scbuf) {
    size_t idx = (size_t)blockIdx.x * 256 + threadIdx.x;
    size_t off = idx * 514 + 512;
    f32x2 v = *(const f32x2*)(x + off);
    *(f32x2*)(out + off) = v;
    *(f32x2*)(scbuf + idx * 2) = v;
}

// ---------------------------------------------------------------------------
// mixer v6: one wg per (b,h). XT (bf16 x^T) stays pristine for the residual;
// stage-2 output overwrites S in place; ST aliases S after stage-3 drains.
// Emits ONLY Xb (bf16) — f32 out central region is never written (gemm2
// reconstructs the residual from Xb).  HBM: read x once + write Xb.
// ---------------------------------------------------------------------------
#define MPAD 264

__global__ __launch_bounds__(256, 2) void mixer_kernel(
    const float* __restrict__ x, const float* __restrict__ bs,
    const float* __restrict__ Hb1, const float* __restrict__ Hb2,
    const unsigned short* __restrict__ Wsb,
    const unsigned short* __restrict__ HW1b,
    const unsigned short* __restrict__ HW2b,
    const float* __restrict__ gb,
    unsigned short* __restrict__ Xb) {
    __shared__ __attribute__((aligned(16))) char smem[33792 + 34816];
    unsigned short* XT = (unsigned short*)smem;            // [64][264] bf16 x^T
    unsigned short* S = (unsigned short*)(smem + 33792);   // [64][264]
    unsigned short* ST = S;                                // alias: [256][68]

    const int bid = blockIdx.x;
    const int b = bid >> 3;
    const int h = bid & 7;
    const int tid = threadIdx.x;
    const int lane = tid & 63;
    const int w = tid >> 6;
    const int l15 = lane & 15;
    const int l4 = lane >> 4;

    // ---- stage x^T into LDS as bf16: XT[c][p] ----
    {
        const int c = lane;
        const float* xp = x + ((size_t)b * 256) * 514 + (size_t)h * 64 + c;
        for (int i = 0; i < 32; ++i) {
            int p = (i * 4 + w) * 2;
            float v0 = xp[(size_t)p * 514];
            float v1 = xp[(size_t)(p + 1) * 514];
            *(unsigned int*)&XT[c * MPAD + p] = pack2(v0, v1);
        }
    }
    __syncthreads();

    f32x4 acc[4][4];

    // ---- stage 1: S[c][o] = (XT @ Ws^T + bs)*gamma + beta ----
    #pragma unroll
    for (int mt = 0; mt < 4; ++mt)
        #pragma unroll
        for (int nt = 0; nt < 4; ++nt) acc[mt][nt] = 0.f;
    {
        bf16x8 bnx[4];
        #pragma unroll
        for (int nt = 0; nt < 4; ++nt)
            bnx[nt] = *(const bf16x8*)(Wsb + (size_t)(w * 64 + nt * 16 + l15) * 256 + l4 * 8);
        for (int kc = 0; kc < 8; ++kc) {
            bf16x8 bcur[4];
            #pragma unroll
            for (int nt = 0; nt < 4; ++nt) bcur[nt] = bnx[nt];
            if (kc < 7) {
                #pragma unroll
                for (int nt = 0; nt < 4; ++nt)
                    bnx[nt] = *(const bf16x8*)(Wsb + (size_t)(w * 64 + nt * 16 + l15) * 256 + (kc + 1) * 32 + l4 * 8);
            }
            #pragma unroll
            for (int mt = 0; mt < 4; ++mt) {
                bf16x8 afr = *(const bf16x8*)&XT[(mt * 16 + l15) * MPAD + kc * 32 + l4 * 8];
                #pragma unroll
                for (int nt = 0; nt < 4; ++nt)
                    acc[mt][nt] = __builtin_amdgcn_mfma_f32_16x16x32_bf16(afr, bcur[nt], acc[mt][nt], 0, 0, 0);
            }
        }
    }
    #pragma unroll
    for (int nt = 0; nt < 4; ++nt) {
        int o = w * 64 + nt * 16 + l15;
        float bsv = bs[o];
        float g = gb[(size_t)b * 512 + o];
        float be = gb[(size_t)b * 512 + 256 + o];
        #pragma unroll
        for (int mt = 0; mt < 4; ++mt)
            #pragma unroll
            for (int r = 0; r < 4; ++r) {
                int c = mt * 16 + l4 * 4 + r;
                S[c * MPAD + o] = f2bf((acc[mt][nt][r] + bsv) * g + be);
            }
    }
    __syncthreads();

    // ---- stage 2: S <- gelu(S @ HW1[h]^T + Hb1[h])  (in place) ----
    const unsigned short* W2p = HW1b + (size_t)h * 65536;
    #pragma unroll
    for (int mt = 0; mt < 4; ++mt)
        #pragma unroll
        for (int nt = 0; nt < 4; ++nt) acc[mt][nt] = 0.f;
    {
        bf16x8 bnx[4];
        #pragma unroll
        for (int nt = 0; nt < 4; ++nt)
            bnx[nt] = *(const bf16x8*)(W2p + (size_t)(w * 64 + nt * 16 + l15) * 256 + l4 * 8);
        for (int kc = 0; kc < 8; ++kc) {
            bf16x8 bcur[4];
            #pragma unroll
            for (int nt = 0; nt < 4; ++nt) bcur[nt] = bnx[nt];
            if (kc < 7) {
                #pragma unroll
                for (int nt = 0; nt < 4; ++nt)
                    bnx[nt] = *(const bf16x8*)(W2p + (size_t)(w * 64 + nt * 16 + l15) * 256 + (kc + 1) * 32 + l4 * 8);
            }
            #pragma unroll
            for (int mt = 0; mt < 4; ++mt) {
                bf16x8 afr = *(const bf16x8*)&S[(mt * 16 + l15) * MPAD + kc * 32 + l4 * 8];
                #pragma unroll
                for (int nt = 0; nt < 4; ++nt)
                    acc[mt][nt] = __builtin_amdgcn_mfma_f32_16x16x32_bf16(afr, bcur[nt], acc[mt][nt], 0, 0, 0);
            }
        }
    }
    __syncthreads();  // all S reads complete before in-place overwrite
    #pragma unroll
    for (int nt = 0; nt < 4; ++nt) {
        int kk = w * 64 + nt * 16 + l15;
        float hb = Hb1[(size_t)h * 256 + kk];
        #pragma unroll
        for (int mt = 0; mt < 4; ++mt)
            #pragma unroll
            for (int r = 0; r < 4; ++r) {
                int c = mt * 16 + l4 * 4 + r;
                S[c * MPAD + kk] = f2bf(gelu_fast(acc[mt][nt][r] + hb));
            }
    }
    __syncthreads();

    // ---- stage 3: acc = S(=T) @ HW2[h]^T ----
    const unsigned short* W3p = HW2b + (size_t)h * 65536;
    #pragma unroll
    for (int mt = 0; mt < 4; ++mt)
        #pragma unroll
        for (int nt = 0; nt < 4; ++nt) acc[mt][nt] = 0.f;
    {
        bf16x8 bnx[4];
        #pragma unroll
        for (int nt = 0; nt < 4; ++nt)
            bnx[nt] = *(const bf16x8*)(W3p + (size_t)(w * 64 + nt * 16 + l15) * 256 + l4 * 8);
        for (int kc = 0; kc < 8; ++kc) {
            bf16x8 bcur[4];
            #pragma unroll
            for (int nt = 0; nt < 4; ++nt) bcur[nt] = bnx[nt];
            if (kc < 7) {
                #pragma unroll
                for (int nt = 0; nt < 4; ++nt)
                    bnx[nt] = *(const bf16x8*)(W3p + (size_t)(w * 64 + nt * 16 + l15) * 256 + (kc + 1) * 32 + l4 * 8);
            }
            #pragma unroll
            for (int mt = 0; mt < 4; ++mt) {
                bf16x8 afr = *(const bf16x8*)&S[(mt * 16 + l15) * MPAD + kc * 32 + l4 * 8];
                #pragma unroll
                for (int nt = 0; nt < 4; ++nt)
                    acc[mt][nt] = __builtin_amdgcn_mfma_f32_16x16x32_bf16(afr, bcur[nt], acc[mt][nt], 0, 0, 0);
            }
        }
    }
    __syncthreads();  // all S reads complete before ST (alias) writes

    // ---- ST[p][c] = stage3 + Hb2 + residual (from pristine XT) ----
    #pragma unroll
    for (int nt = 0; nt < 4; ++nt) {
        int p = w * 64 + nt * 16 + l15;
        float hb = Hb2[(size_t)h * 256 + p];
        #pragma unroll
        for (int mt = 0; mt < 4; ++mt) {
            int c0 = mt * 16 + l4 * 4;
            ushort4 uv;
            uv.x = f2bf(acc[mt][nt][0] + hb + bf2f(XT[(c0 + 0) * MPAD + p]));
            uv.y = f2bf(acc[mt][nt][1] + hb + bf2f(XT[(c0 + 1) * MPAD + p]));
            uv.z = f2bf(acc[mt][nt][2] + hb + bf2f(XT[(c0 + 2) * MPAD + p]));
            uv.w = f2bf(acc[mt][nt][3] + hb + bf2f(XT[(c0 + 3) * MPAD + p]));
            *(ushort4*)(ST + p * 68 + c0) = uv;
        }
    }
    __syncthreads();

    // ---- coalesced copy-out: Xb only ----
    #pragma unroll
    for (int s = 0; s < 16; ++s) {
        int row = s * 16 + w * 4 + l4;
        ushort4 u = *(const ushort4*)(ST + row * 68 + l15 * 4);
        *(ushort4*)(Xb + ((size_t)(b * 256 + row)) * 512 + h * 64 + l15 * 4) = u;
    }
}

// ---------------------------------------------------------------------------
// GEMM v4: 256x256 tile, BK=64, 8 waves as 2M x 4N (wave tile 128x64).
// ONE barrier per K-tile; vmcnt(0) drain; LDS 128KB (A 2x32K, B 2x32K).
// ---------------------------------------------------------------------------
DEV void stage_half(const unsigned short* g, size_t gstride, int row0, int k0,
                    char* half_base, int w, int lane) {
    const int slot = lane & 7;
    const int r8 = lane >> 3;
    const int swz = (slot ^ r8) * 16;
    #pragma unroll
    for (int i = 0; i < 2; ++i) {
        int chunk = w * 2 + i;  // 0..15 within half
        int row = chunk * 8 + r8;
        const char* src = (const char*)(g + (size_t)(row0 + row) * gstride + k0) + swz;
        __builtin_amdgcn_global_load_lds((const glb_u32*)src,
                                         (lds_u32*)(half_base + chunk * 1024), 16, 0, 0);
    }
}

DEV void stage4(const unsigned short* A, size_t sA, int m0,
                const unsigned short* B, size_t sB, int n0, int k0,
                char* Abuf, char* Bbuf, int w, int lane) {
    stage_half(A, sA, m0, k0, Abuf, w, lane);
    stage_half(A, sA, m0 + 128, k0, Abuf + 16384, w, lane);
    stage_half(B, sB, n0, k0, Bbuf, w, lane);
    stage_half(B, sB, n0 + 128, k0, Bbuf + 16384, w, lane);
}

DEV void tile_body(const unsigned short* A, size_t sA, int m0,
                   const unsigned short* B, size_t sB, int n0,
                   char* smem, int cb, int kn, bool more,
                   int vA0, int vA1, int vB0, int vB1,
                   int w, int lane, f32x4 (&acc)[8][4]) {
    if (more) {
        int nb = 32768 - cb;
        stage4(A, sA, m0, B, sB, n0, kn, smem + nb, smem + 65536 + nb, w, lane);
    }
    __builtin_amdgcn_s_setprio(1);
    #pragma unroll
    for (int kk = 0; kk < 2; ++kk) {
        const int vA = kk ? vA1 : vA0;
        const int vB = kk ? vB1 : vB0;
        bf16x8 bf[4];
        #pragma unroll
        for (int nf = 0; nf < 4; ++nf)
            bf[nf] = *(const bf16x8*)(smem + vB + cb + nf * 2048);
        #pragma unroll
        for (int mh = 0; mh < 2; ++mh) {
            bf16x8 af[4];
            #pragma unroll
            for (int mf = 0; mf < 4; ++mf)
                af[mf] = *(const bf16x8*)(smem + vA + cb + mh * 8192 + mf * 2048);
            #pragma unroll
            for (int mf = 0; mf < 4; ++mf)
                #pragma unroll
                for (int nf = 0; nf < 4; ++nf)
                    acc[mh * 4 + mf][nf] = __builtin_amdgcn_mfma_f32_16x16x32_bf16(
                        af[mf], bf[nf], acc[mh * 4 + mf][nf], 0, 0, 0);
        }
    }
    __builtin_amdgcn_s_setprio(0);
    if (more) asm volatile("s_waitcnt vmcnt(0)" ::: "memory");
    __builtin_amdgcn_s_barrier();
}

DEV void gemm_loop(const unsigned short* A, size_t sA,
                   const unsigned short* B, size_t sB,
                   int m0, int n0, int NT,
                   char* smem, int w, int lane, f32x4 (&acc)[8][4]) {
    const int wm = w >> 2, wn = w & 3;
    const int l15 = lane & 15, l4 = lane >> 4;
    const int sw = (l15 & 7) << 4;
    const int k0off = (l4 * 16) ^ sw;
    const int k1off = (64 + l4 * 16) ^ sw;
    const int aBase = (wm * 128 + l15) * 128;
    const int bBase = 65536 + (wn * 64 + l15) * 128;
    const int vA0 = aBase + k0off, vA1 = aBase + k1off;
    const int vB0 = bBase + k0off, vB1 = bBase + k1off;

    stage4(A, sA, m0, B, sB, n0, 0, smem, smem + 65536, w, lane);
    asm volatile("s_waitcnt vmcnt(0)" ::: "memory");
    __builtin_amdgcn_s_barrier();

    for (int t = 0; t < NT; t += 2) {
        tile_body(A, sA, m0, B, sB, n0, smem, 0, (t + 1) * 64, t + 1 < NT,
                  vA0, vA1, vB0, vB1, w, lane, acc);
        tile_body(A, sA, m0, B, sB, n0, smem, 32768, (t + 2) * 64, t + 2 < NT,
                  vA0, vA1, vB0, vB1, w, lane, acc);
    }
}

// GEMM1: G = gelu(Xb @ FW1b^T + Fb1 + sc0*w512 + sc1*w513), coalesced via LDS bounce
__global__ __launch_bounds__(512, 1) void gemm1_kernel(
    const unsigned short* __restrict__ A,
    const unsigned short* __restrict__ B,
    const float* __restrict__ Fb1,
    const float* __restrict__ FW1,
    const float* __restrict__ scbuf,
    long pass_m0,
    unsigned short* __restrict__ G) {
    __shared__ __attribute__((aligned(16))) char smem[131072];

    const int nwg = gridDim.x;
    const int cpx = nwg >> 3;
    const int bid = (blockIdx.x & 7) * cpx + (blockIdx.x >> 3);
    const int m0 = (bid >> 3) * 256;
    const int n0 = (bid & 7) * 256;
    const int tid = threadIdx.x;
    const int lane = tid & 63;
    const int w = tid >> 6;
    const int l15 = lane & 15;
    const int l4 = lane >> 4;
    const int wm = w >> 2, wn = w & 3;

    f32x4 acc[8][4];
    #pragma unroll
    for (int mf = 0; mf < 8; ++mf)
        #pragma unroll
        for (int nf = 0; nf < 4; ++nf) acc[mf][nf] = 0.f;

    gemm_loop(A, 512, B, 512, m0, n0, 8, smem, w, lane, acc);

    // epilogue: bias + sc + gelu -> bf16, LDS bounce (pitch 264) for coalesced stores
    float fb[4], wa[4], wb[4];
    #pragma unroll
    for (int nf = 0; nf < 4; ++nf) {
        int n = n0 + wn * 64 + nf * 16 + l15;
        fb[nf] = Fb1[n];
        wa[nf] = FW1[(size_t)n * 514 + 512];
        wb[nf] = FW1[(size_t)n * 514 + 513];
    }
    unsigned short* LT = (unsigned short*)smem;  // [128][264] (528B pitch)
    #pragma unroll
    for (int ph = 0; ph < 2; ++ph) {
        if (wm == ph) {
            #pragma unroll
            for (int mfg = 0; mfg < 8; ++mfg) {
                f32x2 sc[4];
                #pragma unroll
                for (int r = 0; r < 4; ++r) {
                    long rowg = pass_m0 + m0 + ph * 128 + mfg * 16 + l4 * 4 + r;
                    sc[r] = *(const f32x2*)(scbuf + rowg * 2);
                }
                #pragma unroll
                for (int nf = 0; nf < 4; ++nf)
                    #pragma unroll
                    for (int r = 0; r < 4; ++r) {
                        float v = acc[mfg][nf][r] + fb[nf] + sc[r].x * wa[nf] + sc[r].y * wb[nf];
                        int rl = mfg * 16 + l4 * 4 + r;
                        LT[rl * 264 + wn * 64 + nf * 16 + l15] = f2bf(gelu_fast(v));
                    }
            }
        }
        __syncthreads();
        {
            const int row16 = tid >> 5, col16 = tid & 31;
            #pragma unroll
            for (int sp = 0; sp < 8; ++sp) {
                int row = sp * 16 + row16;
                uint4 d = *(const uint4*)((const char*)smem + row * 528 + col16 * 16);
                *(uint4*)(G + ((size_t)(m0 + ph * 128 + row)) * 2048 + n0 + col16 * 8) = d;
            }
        }
        __syncthreads();
    }
}

// GEMM2: io[., 0..511] = G @ FW2b^T + Fb2 + bf2f(Xb)   (residual from Xb)
__global__ __launch_bounds__(512, 1) void gemm2_kernel(
    const unsigned short* __restrict__ A,
    const unsigned short* __restrict__ B,
    const float* __restrict__ Fb2,
    const unsigned short* __restrict__ Xb,
    long pass_m0,
    float* __restrict__ io) {
    __shared__ __attribute__((aligned(16))) char smem[131072];

    const int nwg = gridDim.x;
    const int cpx = nwg >> 3;
    const int bid = (blockIdx.x & 7) * cpx + (blockIdx.x >> 3);
    const int m0 = (bid >> 1) * 256;
    const int n0 = (bid & 1) * 256;
    const int tid = threadIdx.x;
    const int lane = tid & 63;
    const int w = tid >> 6;
    const int l15 = lane & 15;
    const int l4 = lane >> 4;
    const int wm = w >> 2, wn = w & 3;

    f32x4 acc[8][4];
    #pragma unroll
    for (int mf = 0; mf < 8; ++mf)
        #pragma unroll
        for (int nf = 0; nf < 4; ++nf) acc[mf][nf] = 0.f;

    gemm_loop(A, 2048, B, 2048, m0, n0, 32, smem, w, lane, acc);

    #pragma unroll
    for (int nf = 0; nf < 4; ++nf) {
        int n = n0 + wn * 64 + nf * 16 + l15;
        float fbv = Fb2[n];
        #pragma unroll
        for (int mfg = 0; mfg < 8; ++mfg)
            #pragma unroll
            for (int r = 0; r < 4; ++r) {
                long rowg = pass_m0 + m0 + wm * 128 + mfg * 16 + l4 * 4 + r;
                float resv = bf2f(Xb[(size_t)rowg * 512 + n]);
                io[rowg * 514 + n] = acc[mfg][nf][r] + fbv + resv;
            }
    }
}

// ---------------------------------------------------------------------------
extern "C" void kernel_launch(void* const* d_in, const int* in_sizes, int n_in,
                              void* d_out, int out_size, void* d_ws, size_t ws_size,
                              hipStream_t stream) {
    const float* x = (const float*)d_in[0];
    const float* Ws = (const float*)d_in[1];
    const float* bs = (const float*)d_in[2];
    const float* LW1 = (const float*)d_in[3];
    const float* Lb1 = (const float*)d_in[4];
    const float* LW2 = (const float*)d_in[5];
    const float* Lb2 = (const float*)d_in[6];
    const float* HW1 = (const float*)d_in[7];
    const float* Hb1 = (const float*)d_in[8];
    const float* HW2 = (const float*)d_in[9];
    const float* Hb2 = (const float*)d_in[10];
    const float* FW1 = (const float*)d_in[11];
    const float* Fb1 = (const float*)d_in[12];
    const float* FW2 = (const float*)d_in[13];
    const float* Fb2 = (const float*)d_in[14];
    float* out = (float*)d_out;

    char* ws = (char*)d_ws;
    unsigned short* Wsb = (unsigned short*)(ws);                 // 131072 B
    unsigned short* HW1b = (unsigned short*)(ws + 131072);       // 1048576 B
    unsigned short* HW2b = (unsigned short*)(ws + 1179648);      // 1048576 B
    unsigned short* FW1b = (unsigned short*)(ws + 2228224);      // 2097152 B
    unsigned short* FW2b = (unsigned short*)(ws + 4325376);      // 2097152 B
    float* gb = (float*)(ws + 6422528);                          // 524288 B
    float* scbuf = (float*)(ws + 6946816);                       // 524288 B
    unsigned short* Xb = (unsigned short*)(ws + 7471104);        // 67108864 B
    unsigned short* Gbuf = (unsigned short*)(ws + 7471104 + 67108864);

    const size_t fixed = 7471104 + 67108864;
    int npass = 32;
    for (int np = 2; np <= 32; np *= 2) {
        if (fixed + (size_t)268435456 / np <= ws_size) { npass = np; break; }
    }
    const long Mtot = 65536;
    const long Mp = Mtot / npass;

    cast_bf16_kernel<<<256, 256, 0, stream>>>(Ws, Wsb, 65536);
    cast_bf16_kernel<<<2048, 256, 0, stream>>>(HW1, HW1b, 524288);
    cast_bf16_kernel<<<2048, 256, 0, stream>>>(HW2, HW2b, 524288);
    cast_bf16_kernel<<<4096, 256, 0, stream>>>(FW2, FW2b, 1048576);
    cast_fw1_kernel<<<4096, 256, 0, stream>>>(FW1, FW1b);
    gb_kernel<<<32, 256, 0, stream>>>(x, LW1, Lb1, LW2, Lb2, gb);
    sc_copy_kernel<<<256, 256, 0, stream>>>(x, out, scbuf);

    mixer_kernel<<<2048, 256, 0, stream>>>(x, bs, Hb1, Hb2, Wsb, HW1b, HW2b, gb, Xb);

    for (int p = 0; p < npass; ++p) {
        long m0 = (long)p * Mp;
        gemm1_kernel<<<(int)(Mp / 256) * 8, 512, 0, stream>>>(
            Xb + m0 * 512, FW1b, Fb1, FW1, scbuf, m0, Gbuf);
        gemm2_kernel<<<(int)(Mp / 256) * 2, 512, 0, stream>>>(
            Gbuf, FW2b, Fb2, Xb, m0, out);
    }
}

// Round 10
// 601.148 us; speedup vs baseline: 1.1889x; 1.1075x over previous
//
#include <hip/hip_runtime.h>
#include <math.h>

typedef __attribute__((ext_vector_type(8))) __bf16 bf16x8;
typedef __attribute__((ext_vector_type(4))) float f32x4;
typedef __attribute__((ext_vector_type(2))) float f32x2;

#define DEV __device__ __forceinline__

typedef __attribute__((address_space(3))) unsigned int lds_u32;
typedef __attribute__((address_space(1))) unsigned int glb_u32;

DEV unsigned short f2bf(float f) {
    unsigned int u = __builtin_bit_cast(unsigned int, f);
    u += 0x7FFFu + ((u >> 16) & 1u);
    return (unsigned short)(u >> 16);
}
DEV float bf2f(unsigned short u) {
    unsigned int v = (unsigned int)u << 16;
    return __builtin_bit_cast(float, v);
}
DEV unsigned int pack2(float a, float b) {
    return (unsigned int)f2bf(a) | ((unsigned int)f2bf(b) << 16);
}
DEV float gelu_exact(float v) {
    return 0.5f * v * (1.0f + erff(v * 0.70710678118654752f));
}
// tanh-form gelu via sigmoid: x * sigmoid(1.595769x + 0.0713548x^3); |err| <= 3e-3
DEV float gelu_fast(float x) {
    float z = 1.5957691216f * x + 0.0713548163f * x * x * x;
    float e = __expf(-z);
    return x * __builtin_amdgcn_rcpf(1.0f + e);
}

// ---------------------------------------------------------------------------
// small prep kernels
// ---------------------------------------------------------------------------
__global__ void cast_bf16_kernel(const float* __restrict__ src,
                                 unsigned short* __restrict__ dst, int n) {
    int i = blockIdx.x * 256 + threadIdx.x;
    if (i < n) dst[i] = f2bf(src[i]);
}

__global__ void cast_fw1_kernel(const float* __restrict__ src,
                                unsigned short* __restrict__ dst) {
    int i = blockIdx.x * 256 + threadIdx.x;
    if (i < 2048 * 512) {
        int row = i >> 9, k = i & 511;
        dst[i] = f2bf(src[row * 514 + k]);
    }
}

__global__ void gb_kernel(const float* __restrict__ x,
                          const float* __restrict__ LW1, const float* __restrict__ Lb1,
                          const float* __restrict__ LW2, const float* __restrict__ Lb2,
                          float* __restrict__ gb) {
    __shared__ float t[8][512];
    const int b0 = blockIdx.x * 8, tid = threadIdx.x;
    for (int idx = tid; idx < 8 * 512; idx += 256) {
        int bb = idx >> 9, j = idx & 511;
        float s0 = x[((size_t)(b0 + bb) * 256 + 128) * 514 + 512];
        float s1 = x[((size_t)(b0 + bb) * 256 + 128) * 514 + 513];
        t[bb][j] = gelu_exact(LW1[j * 2] * s0 + LW1[j * 2 + 1] * s1 + Lb1[j]);
    }
    __syncthreads();
    const int i = tid;
    float a0[8], a1[8];
    float l0 = Lb2[i], l1 = Lb2[i + 256];
    #pragma unroll
    for (int bb = 0; bb < 8; ++bb) { a0[bb] = l0; a1[bb] = l1; }
    for (int j = 0; j < 512; ++j) {
        float w0 = LW2[(size_t)i * 512 + j];
        float w1 = LW2[(size_t)(i + 256) * 512 + j];
        #pragma unroll
        for (int bb = 0; bb < 8; ++bb) {
            a0[bb] += w0 * t[bb][j];
            a1[bb] += w1 * t[bb][j];
        }
    }
    #pragma unroll
    for (int bb = 0; bb < 8; ++bb) {
        gb[(size_t)(b0 + bb) * 512 + i] = a0[bb];
        gb[(size_t)(b0 + bb) * 512 + i + 256] = a1[bb];
    }
}

__global__ void sc_copy_kernel(const float* __restrict__ x, float* __restrict__ out,
                               float* __restrict__ scbuf) {
    size_t idx = (size_t)blockIdx.x * 256 + threadIdx.x;
    size_t off = idx * 514 + 512;
    f32x2 v = *(const f32x2*)(x + off);
    *(f32x2*)(out + off) = v;
    *(f32x2*)(scbuf + idx * 2) = v;
}

// ---------------------------------------------------------------------------
// mixer v7: as v6 but staging writes XT via b128 (8 p packed per write).
// ---------------------------------------------------------------------------
#define MPAD 264

__global__ __launch_bounds__(256, 2) void mixer_kernel(
    const float* __restrict__ x, const float* __restrict__ bs,
    const float* __restrict__ Hb1, const float* __restrict__ Hb2,
    const unsigned short* __restrict__ Wsb,
    const unsigned short* __restrict__ HW1b,
    const unsigned short* __restrict__ HW2b,
    const float* __restrict__ gb,
    unsigned short* __restrict__ Xb) {
    __shared__ __attribute__((aligned(16))) char smem[33792 + 34816];
    unsigned short* XT = (unsigned short*)smem;            // [64][264] bf16 x^T
    unsigned short* S = (unsigned short*)(smem + 33792);   // [64][264]
    unsigned short* ST = S;                                // alias: [256][68]

    const int bid = blockIdx.x;
    const int b = bid >> 3;
    const int h = bid & 7;
    const int tid = threadIdx.x;
    const int lane = tid & 63;
    const int w = tid >> 6;
    const int l15 = lane & 15;
    const int l4 = lane >> 4;

    // ---- stage x^T into LDS as bf16: XT[c][p], b128 writes (8 p per write) ----
    {
        const int c = lane;
        const float* xp = x + ((size_t)b * 256) * 514 + (size_t)h * 64 + c;
        #pragma unroll
        for (int g = 0; g < 8; ++g) {
            int p0 = w * 64 + g * 8;
            float v0 = xp[(size_t)(p0 + 0) * 514];
            float v1 = xp[(size_t)(p0 + 1) * 514];
            float v2 = xp[(size_t)(p0 + 2) * 514];
            float v3 = xp[(size_t)(p0 + 3) * 514];
            float v4 = xp[(size_t)(p0 + 4) * 514];
            float v5 = xp[(size_t)(p0 + 5) * 514];
            float v6 = xp[(size_t)(p0 + 6) * 514];
            float v7 = xp[(size_t)(p0 + 7) * 514];
            uint4 pk;
            pk.x = pack2(v0, v1);
            pk.y = pack2(v2, v3);
            pk.z = pack2(v4, v5);
            pk.w = pack2(v6, v7);
            *(uint4*)&XT[c * MPAD + p0] = pk;
        }
    }
    __syncthreads();

    f32x4 acc[4][4];

    // ---- stage 1: S[c][o] = (XT @ Ws^T + bs)*gamma + beta ----
    #pragma unroll
    for (int mt = 0; mt < 4; ++mt)
        #pragma unroll
        for (int nt = 0; nt < 4; ++nt) acc[mt][nt] = 0.f;
    {
        bf16x8 bnx[4];
        #pragma unroll
        for (int nt = 0; nt < 4; ++nt)
            bnx[nt] = *(const bf16x8*)(Wsb + (size_t)(w * 64 + nt * 16 + l15) * 256 + l4 * 8);
        for (int kc = 0; kc < 8; ++kc) {
            bf16x8 bcur[4];
            #pragma unroll
            for (int nt = 0; nt < 4; ++nt) bcur[nt] = bnx[nt];
            if (kc < 7) {
                #pragma unroll
                for (int nt = 0; nt < 4; ++nt)
                    bnx[nt] = *(const bf16x8*)(Wsb + (size_t)(w * 64 + nt * 16 + l15) * 256 + (kc + 1) * 32 + l4 * 8);
            }
            #pragma unroll
            for (int mt = 0; mt < 4; ++mt) {
                bf16x8 afr = *(const bf16x8*)&XT[(mt * 16 + l15) * MPAD + kc * 32 + l4 * 8];
                #pragma unroll
                for (int nt = 0; nt < 4; ++nt)
                    acc[mt][nt] = __builtin_amdgcn_mfma_f32_16x16x32_bf16(afr, bcur[nt], acc[mt][nt], 0, 0, 0);
            }
        }
    }
    #pragma unroll
    for (int nt = 0; nt < 4; ++nt) {
        int o = w * 64 + nt * 16 + l15;
        float bsv = bs[o];
        float g = gb[(size_t)b * 512 + o];
        float be = gb[(size_t)b * 512 + 256 + o];
        #pragma unroll
        for (int mt = 0; mt < 4; ++mt)
            #pragma unroll
            for (int r = 0; r < 4; ++r) {
                int c = mt * 16 + l4 * 4 + r;
                S[c * MPAD + o] = f2bf((acc[mt][nt][r] + bsv) * g + be);
            }
    }
    __syncthreads();

    // ---- stage 2: S <- gelu(S @ HW1[h]^T + Hb1[h])  (in place) ----
    const unsigned short* W2p = HW1b + (size_t)h * 65536;
    #pragma unroll
    for (int mt = 0; mt < 4; ++mt)
        #pragma unroll
        for (int nt = 0; nt < 4; ++nt) acc[mt][nt] = 0.f;
    {
        bf16x8 bnx[4];
        #pragma unroll
        for (int nt = 0; nt < 4; ++nt)
            bnx[nt] = *(const bf16x8*)(W2p + (size_t)(w * 64 + nt * 16 + l15) * 256 + l4 * 8);
        for (int kc = 0; kc < 8; ++kc) {
            bf16x8 bcur[4];
            #pragma unroll
            for (int nt = 0; nt < 4; ++nt) bcur[nt] = bnx[nt];
            if (kc < 7) {
                #pragma unroll
                for (int nt = 0; nt < 4; ++nt)
                    bnx[nt] = *(const bf16x8*)(W2p + (size_t)(w * 64 + nt * 16 + l15) * 256 + (kc + 1) * 32 + l4 * 8);
            }
            #pragma unroll
            for (int mt = 0; mt < 4; ++mt) {
                bf16x8 afr = *(const bf16x8*)&S[(mt * 16 + l15) * MPAD + kc * 32 + l4 * 8];
                #pragma unroll
                for (int nt = 0; nt < 4; ++nt)
                    acc[mt][nt] = __builtin_amdgcn_mfma_f32_16x16x32_bf16(afr, bcur[nt], acc[mt][nt], 0, 0, 0);
            }
        }
    }
    __syncthreads();  // all S reads complete before in-place overwrite
    #pragma unroll
    for (int nt = 0; nt < 4; ++nt) {
        int kk = w * 64 + nt * 16 + l15;
        float hb = Hb1[(size_t)h * 256 + kk];
        #pragma unroll
        for (int mt = 0; mt < 4; ++mt)
            #pragma unroll
            for (int r = 0; r < 4; ++r) {
                int c = mt * 16 + l4 * 4 + r;
                S[c * MPAD + kk] = f2bf(gelu_fast(acc[mt][nt][r] + hb));
            }
    }
    __syncthreads();

    // ---- stage 3: acc = S(=T) @ HW2[h]^T ----
    const unsigned short* W3p = HW2b + (size_t)h * 65536;
    #pragma unroll
    for (int mt = 0; mt < 4; ++mt)
        #pragma unroll
        for (int nt = 0; nt < 4; ++nt) acc[mt][nt] = 0.f;
    {
        bf16x8 bnx[4];
        #pragma unroll
        for (int nt = 0; nt < 4; ++nt)
            bnx[nt] = *(const bf16x8*)(W3p + (size_t)(w * 64 + nt * 16 + l15) * 256 + l4 * 8);
        for (int kc = 0; kc < 8; ++kc) {
            bf16x8 bcur[4];
            #pragma unroll
            for (int nt = 0; nt < 4; ++nt) bcur[nt] = bnx[nt];
            if (kc < 7) {
                #pragma unroll
                for (int nt = 0; nt < 4; ++nt)
                    bnx[nt] = *(const bf16x8*)(W3p + (size_t)(w * 64 + nt * 16 + l15) * 256 + (kc + 1) * 32 + l4 * 8);
            }
            #pragma unroll
            for (int mt = 0; mt < 4; ++mt) {
                bf16x8 afr = *(const bf16x8*)&S[(mt * 16 + l15) * MPAD + kc * 32 + l4 * 8];
                #pragma unroll
                for (int nt = 0; nt < 4; ++nt)
                    acc[mt][nt] = __builtin_amdgcn_mfma_f32_16x16x32_bf16(afr, bcur[nt], acc[mt][nt], 0, 0, 0);
            }
        }
    }
    __syncthreads();  // all S reads complete before ST (alias) writes

    // ---- ST[p][c] = stage3 + Hb2 + residual (from pristine XT) ----
    #pragma unroll
    for (int nt = 0; nt < 4; ++nt) {
        int p = w * 64 + nt * 16 + l15;
        float hb = Hb2[(size_t)h * 256 + p];
        #pragma unroll
        for (int mt = 0; mt < 4; ++mt) {
            int c0 = mt * 16 + l4 * 4;
            ushort4 uv;
            uv.x = f2bf(acc[mt][nt][0] + hb + bf2f(XT[(c0 + 0) * MPAD + p]));
            uv.y = f2bf(acc[mt][nt][1] + hb + bf2f(XT[(c0 + 1) * MPAD + p]));
            uv.z = f2bf(acc[mt][nt][2] + hb + bf2f(XT[(c0 + 2) * MPAD + p]));
            uv.w = f2bf(acc[mt][nt][3] + hb + bf2f(XT[(c0 + 3) * MPAD + p]));
            *(ushort4*)(ST + p * 68 + c0) = uv;
        }
    }
    __syncthreads();

    // ---- coalesced copy-out: Xb only ----
    #pragma unroll
    for (int s = 0; s < 16; ++s) {
        int row = s * 16 + w * 4 + l4;
        ushort4 u = *(const ushort4*)(ST + row * 68 + l15 * 4);
        *(ushort4*)(Xb + ((size_t)(b * 256 + row)) * 512 + h * 64 + l15 * 4) = u;
    }
}

// ---------------------------------------------------------------------------
// GEMM v5 (m97 template): 128x128 tile, BK=64, 256 threads / 4 waves
// (wave tile 64x64, acc 4x4), SINGLE 32KB LDS buffer, stage -> barrier ->
// compute -> barrier. ~3 blocks/CU so stage stalls overlap across blocks.
// ---------------------------------------------------------------------------
DEV void stage_m97(const unsigned short* g, size_t gstride, int row0, int k0,
                   char* lbuf, int tid) {
    const int slot = tid & 7;
    const int r8 = (tid >> 3) & 7;
    const int wv = tid >> 6;
    const int swz = (slot ^ r8) * 16;
    #pragma unroll
    for (int i = 0; i < 4; ++i) {
        int chunk = i * 4 + wv;  // 0..15, wave-uniform
        int row = chunk * 8 + r8;
        const char* src = (const char*)(g + (size_t)(row0 + row) * gstride + k0) + swz;
        __builtin_amdgcn_global_load_lds((const glb_u32*)src,
                                         (lds_u32*)(lbuf + chunk * 1024), 16, 0, 0);
    }
}

DEV void gemm_loop97(const unsigned short* A, size_t sA,
                     const unsigned short* B, size_t sB,
                     int m0, int n0, int NT,
                     char* smem, int tid, f32x4 (&acc)[4][4]) {
    const int lane = tid & 63;
    const int w = tid >> 6;
    const int l15 = lane & 15, l4 = lane >> 4;
    const int wm = w >> 1, wn = w & 1;

    for (int t = 0; t < NT; ++t) {
        stage_m97(A, sA, m0, t * 64, smem, tid);
        stage_m97(B, sB, n0, t * 64, smem + 16384, tid);
        __syncthreads();  // compiler drains vmcnt before barrier
        #pragma unroll
        for (int kk = 0; kk < 2; ++kk) {
            bf16x8 af[4], bf[4];
            #pragma unroll
            for (int mf = 0; mf < 4; ++mf) {
                int row = wm * 64 + mf * 16 + l15;
                af[mf] = *(const bf16x8*)(smem + row * 128 + ((kk * 64 + l4 * 16) ^ ((row & 7) << 4)));
            }
            #pragma unroll
            for (int nf = 0; nf < 4; ++nf) {
                int row = wn * 64 + nf * 16 + l15;
                bf[nf] = *(const bf16x8*)(smem + 16384 + row * 128 + ((kk * 64 + l4 * 16) ^ ((row & 7) << 4)));
            }
            #pragma unroll
            for (int mf = 0; mf < 4; ++mf)
                #pragma unroll
                for (int nf = 0; nf < 4; ++nf)
                    acc[mf][nf] = __builtin_amdgcn_mfma_f32_16x16x32_bf16(
                        af[mf], bf[nf], acc[mf][nf], 0, 0, 0);
        }
        __syncthreads();  // reads done before next-tile staging overwrites
    }
}

// GEMM1: G = gelu(Xb @ FW1b^T + Fb1 + sc0*w512 + sc1*w513), LDS-bounce G store
__global__ __launch_bounds__(256, 3) void gemm1_kernel(
    const unsigned short* __restrict__ A,
    const unsigned short* __restrict__ B,
    const float* __restrict__ Fb1,
    const float* __restrict__ FW1,
    const float* __restrict__ scbuf,
    long pass_m0,
    unsigned short* __restrict__ G) {
    __shared__ __attribute__((aligned(16))) char smem[34816];

    const int nwg = gridDim.x;
    const int cpx = nwg >> 3;
    const int bid = (blockIdx.x & 7) * cpx + (blockIdx.x >> 3);
    const int m0 = (bid >> 4) * 128;
    const int n0 = (bid & 15) * 128;
    const int tid = threadIdx.x;
    const int lane = tid & 63;
    const int w = tid >> 6;
    const int l15 = lane & 15;
    const int l4 = lane >> 4;
    const int wm = w >> 1, wn = w & 1;

    f32x4 acc[4][4];
    #pragma unroll
    for (int mf = 0; mf < 4; ++mf)
        #pragma unroll
        for (int nf = 0; nf < 4; ++nf) acc[mf][nf] = 0.f;

    gemm_loop97(A, 512, B, 512, m0, n0, 8, smem, tid, acc);

    // epilogue: bias + sc + gelu -> bf16 into LT [128][136], then coalesced G store
    float fb[4], wa[4], wb[4];
    #pragma unroll
    for (int nf = 0; nf < 4; ++nf) {
        int n = n0 + wn * 64 + nf * 16 + l15;
        fb[nf] = Fb1[n];
        wa[nf] = FW1[(size_t)n * 514 + 512];
        wb[nf] = FW1[(size_t)n * 514 + 513];
    }
    f32x2 sc[4][4];
    #pragma unroll
    for (int mf = 0; mf < 4; ++mf)
        #pragma unroll
        for (int r = 0; r < 4; ++r) {
            long rowg = pass_m0 + m0 + wm * 64 + mf * 16 + l4 * 4 + r;
            sc[mf][r] = *(const f32x2*)(scbuf + rowg * 2);
        }
    unsigned short* LT = (unsigned short*)smem;  // [128][136]
    #pragma unroll
    for (int mf = 0; mf < 4; ++mf)
        #pragma unroll
        for (int nf = 0; nf < 4; ++nf)
            #pragma unroll
            for (int r = 0; r < 4; ++r) {
                float v = acc[mf][nf][r] + fb[nf] + sc[mf][r].x * wa[nf] + sc[mf][r].y * wb[nf];
                int rl = wm * 64 + mf * 16 + l4 * 4 + r;
                LT[rl * 136 + wn * 64 + nf * 16 + l15] = f2bf(gelu_fast(v));
            }
    __syncthreads();
    {
        const int lane16 = tid & 15, rowq = tid >> 4;
        #pragma unroll
        for (int s = 0; s < 8; ++s) {
            int row = s * 16 + rowq;
            uint4 d = *(const uint4*)((const char*)smem + row * 272 + lane16 * 16);
            *(uint4*)(G + ((size_t)(m0 + row)) * 2048 + n0 + lane16 * 8) = d;
        }
    }
}

// GEMM2: io[., 0..511] = G @ FW2b^T + Fb2 + bf2f(Xb)   (residual from Xb)
__global__ __launch_bounds__(256, 3) void gemm2_kernel(
    const unsigned short* __restrict__ A,
    const unsigned short* __restrict__ B,
    const float* __restrict__ Fb2,
    const unsigned short* __restrict__ Xb,
    long pass_m0,
    float* __restrict__ io) {
    __shared__ __attribute__((aligned(16))) char smem[32768];

    const int nwg = gridDim.x;
    const int cpx = nwg >> 3;
    const int bid = (blockIdx.x & 7) * cpx + (blockIdx.x >> 3);
    const int m0 = (bid >> 2) * 128;
    const int n0 = (bid & 3) * 128;
    const int tid = threadIdx.x;
    const int lane = tid & 63;
    const int w = tid >> 6;
    const int l15 = lane & 15;
    const int l4 = lane >> 4;
    const int wm = w >> 1, wn = w & 1;

    f32x4 acc[4][4];
    #pragma unroll
    for (int mf = 0; mf < 4; ++mf)
        #pragma unroll
        for (int nf = 0; nf < 4; ++nf) acc[mf][nf] = 0.f;

    gemm_loop97(A, 2048, B, 2048, m0, n0, 32, smem, tid, acc);

    #pragma unroll
    for (int nf = 0; nf < 4; ++nf) {
        int n = n0 + wn * 64 + nf * 16 + l15;
        float fbv = Fb2[n];
        #pragma unroll
        for (int mf = 0; mf < 4; ++mf)
            #pragma unroll
            for (int r = 0; r < 4; ++r) {
                long rowg = pass_m0 + m0 + wm * 64 + mf * 16 + l4 * 4 + r;
                float resv = bf2f(Xb[(size_t)rowg * 512 + n]);
                io[rowg * 514 + n] = acc[mf][nf][r] + fbv + resv;
            }
    }
}

// ---------------------------------------------------------------------------
extern "C" void kernel_launch(void* const* d_in, const int* in_sizes, int n_in,
                              void* d_out, int out_size, void* d_ws, size_t ws_size,
                              hipStream_t stream) {
    const float* x = (const float*)d_in[0];
    const float* Ws = (const float*)d_in[1];
    const float* bs = (const float*)d_in[2];
    const float* LW1 = (const float*)d_in[3];
    const float* Lb1 = (const float*)d_in[4];
    const float* LW2 = (const float*)d_in[5];
    const float* Lb2 = (const float*)d_in[6];
    const float* HW1 = (const float*)d_in[7];
    const float* Hb1 = (const float*)d_in[8];
    const float* HW2 = (const float*)d_in[9];
    const float* Hb2 = (const float*)d_in[10];
    const float* FW1 = (const float*)d_in[11];
    const float* Fb1 = (const float*)d_in[12];
    const float* FW2 = (const float*)d_in[13];
    const float* Fb2 = (const float*)d_in[14];
    float* out = (float*)d_out;

    char* ws = (char*)d_ws;
    unsigned short* Wsb = (unsigned short*)(ws);                 // 131072 B
    unsigned short* HW1b = (unsigned short*)(ws + 131072);       // 1048576 B
    unsigned short* HW2b = (unsigned short*)(ws + 1179648);      // 1048576 B
    unsigned short* FW1b = (unsigned short*)(ws + 2228224);      // 2097152 B
    unsigned short* FW2b = (unsigned short*)(ws + 4325376);      // 2097152 B
    float* gb = (float*)(ws + 6422528);                          // 524288 B
    float* scbuf = (float*)(ws + 6946816);                       // 524288 B
    unsigned short* Xb = (unsigned short*)(ws + 7471104);        // 67108864 B
    unsigned short* Gbuf = (unsigned short*)(ws + 7471104 + 67108864);

    const size_t fixed = 7471104 + 67108864;
    int npass = 32;
    for (int np = 2; np <= 32; np *= 2) {
        if (fixed + (size_t)268435456 / np <= ws_size) { npass = np; break; }
    }
    const long Mtot = 65536;
    const long Mp = Mtot / npass;

    cast_bf16_kernel<<<256, 256, 0, stream>>>(Ws, Wsb, 65536);
    cast_bf16_kernel<<<2048, 256, 0, stream>>>(HW1, HW1b, 524288);
    cast_bf16_kernel<<<2048, 256, 0, stream>>>(HW2, HW2b, 524288);
    cast_bf16_kernel<<<4096, 256, 0, stream>>>(FW2, FW2b, 1048576);
    cast_fw1_kernel<<<4096, 256, 0, stream>>>(FW1, FW1b);
    gb_kernel<<<32, 256, 0, stream>>>(x, LW1, Lb1, LW2, Lb2, gb);
    sc_copy_kernel<<<256, 256, 0, stream>>>(x, out, scbuf);

    mixer_kernel<<<2048, 256, 0, stream>>>(x, bs, Hb1, Hb2, Wsb, HW1b, HW2b, gb, Xb);

    for (int p = 0; p < npass; ++p) {
        long m0 = (long)p * Mp;
        gemm1_kernel<<<(int)(Mp / 128) * 16, 256, 0, stream>>>(
            Xb + m0 * 512, FW1b, Fb1, FW1, scbuf, m0, Gbuf);
        gemm2_kernel<<<(int)(Mp / 128) * 4, 256, 0, stream>>>(
            Gbuf, FW2b, Fb2, Xb, m0, out);
    }
}

// Round 11
// 594.096 us; speedup vs baseline: 1.2030x; 1.0119x over previous
//
#include <hip/hip_runtime.h>
#include <math.h>

typedef __attribute__((ext_vector_type(8))) __bf16 bf16x8;
typedef __attribute__((ext_vector_type(4))) float f32x4;
typedef __attribute__((ext_vector_type(2))) float f32x2;

#define DEV __device__ __forceinline__

typedef __attribute__((address_space(3))) unsigned int lds_u32;
typedef __attribute__((address_space(1))) unsigned int glb_u32;

DEV unsigned short f2bf(float f) {
    unsigned int u = __builtin_bit_cast(unsigned int, f);
    u += 0x7FFFu + ((u >> 16) & 1u);
    return (unsigned short)(u >> 16);
}
DEV float bf2f(unsigned short u) {
    unsigned int v = (unsigned int)u << 16;
    return __builtin_bit_cast(float, v);
}
DEV unsigned int pack2(float a, float b) {
    return (unsigned int)f2bf(a) | ((unsigned int)f2bf(b) << 16);
}
DEV float gelu_exact(float v) {
    return 0.5f * v * (1.0f + erff(v * 0.70710678118654752f));
}
// tanh-form gelu via sigmoid: x * sigmoid(1.595769x + 0.0713548x^3); |err| <= 3e-3
DEV float gelu_fast(float x) {
    float z = 1.5957691216f * x + 0.0713548163f * x * x * x;
    float e = __expf(-z);
    return x * __builtin_amdgcn_rcpf(1.0f + e);
}

// ---------------------------------------------------------------------------
// small prep kernels
// ---------------------------------------------------------------------------
__global__ void cast_bf16_kernel(const float* __restrict__ src,
                                 unsigned short* __restrict__ dst, int n) {
    int i = blockIdx.x * 256 + threadIdx.x;
    if (i < n) dst[i] = f2bf(src[i]);
}

__global__ void cast_fw1_kernel(const float* __restrict__ src,
                                unsigned short* __restrict__ dst) {
    int i = blockIdx.x * 256 + threadIdx.x;
    if (i < 2048 * 512) {
        int row = i >> 9, k = i & 511;
        dst[i] = f2bf(src[row * 514 + k]);
    }
}

__global__ void gb_kernel(const float* __restrict__ x,
                          const float* __restrict__ LW1, const float* __restrict__ Lb1,
                          const float* __restrict__ LW2, const float* __restrict__ Lb2,
                          float* __restrict__ gb) {
    __shared__ float t[8][512];
    const int b0 = blockIdx.x * 8, tid = threadIdx.x;
    for (int idx = tid; idx < 8 * 512; idx += 256) {
        int bb = idx >> 9, j = idx & 511;
        float s0 = x[((size_t)(b0 + bb) * 256 + 128) * 514 + 512];
        float s1 = x[((size_t)(b0 + bb) * 256 + 128) * 514 + 513];
        t[bb][j] = gelu_exact(LW1[j * 2] * s0 + LW1[j * 2 + 1] * s1 + Lb1[j]);
    }
    __syncthreads();
    const int i = tid;
    float a0[8], a1[8];
    float l0 = Lb2[i], l1 = Lb2[i + 256];
    #pragma unroll
    for (int bb = 0; bb < 8; ++bb) { a0[bb] = l0; a1[bb] = l1; }
    for (int j = 0; j < 512; ++j) {
        float w0 = LW2[(size_t)i * 512 + j];
        float w1 = LW2[(size_t)(i + 256) * 512 + j];
        #pragma unroll
        for (int bb = 0; bb < 8; ++bb) {
            a0[bb] += w0 * t[bb][j];
            a1[bb] += w1 * t[bb][j];
        }
    }
    #pragma unroll
    for (int bb = 0; bb < 8; ++bb) {
        gb[(size_t)(b0 + bb) * 512 + i] = a0[bb];
        gb[(size_t)(b0 + bb) * 512 + i + 256] = a1[bb];
    }
}

__global__ void sc_copy_kernel(const float* __restrict__ x, float* __restrict__ out,
                               float* __restrict__ scbuf) {
    size_t idx = (size_t)blockIdx.x * 256 + threadIdx.x;
    size_t off = idx * 514 + 512;
    f32x2 v = *(const f32x2*)(x + off);
    *(f32x2*)(out + off) = v;
    *(f32x2*)(scbuf + idx * 2) = v;
}

// ---------------------------------------------------------------------------
// mixer v8: two-phase x staging (all 64 loads issued before any LDS write ->
// 8x memory-level parallelism), 2-deep B prefetch in the 3 GEMM stages.
// ---------------------------------------------------------------------------
#define MPAD 264

__global__ __launch_bounds__(256, 2) void mixer_kernel(
    const float* __restrict__ x, const float* __restrict__ bs,
    const float* __restrict__ Hb1, const float* __restrict__ Hb2,
    const unsigned short* __restrict__ Wsb,
    const unsigned short* __restrict__ HW1b,
    const unsigned short* __restrict__ HW2b,
    const float* __restrict__ gb,
    unsigned short* __restrict__ Xb) {
    __shared__ __attribute__((aligned(16))) char smem[33792 + 34816];
    unsigned short* XT = (unsigned short*)smem;            // [64][264] bf16 x^T
    unsigned short* S = (unsigned short*)(smem + 33792);   // [64][264]
    unsigned short* ST = S;                                // alias: [256][68]

    const int bid = blockIdx.x;
    const int b = bid >> 3;
    const int h = bid & 7;
    const int tid = threadIdx.x;
    const int lane = tid & 63;
    const int w = tid >> 6;
    const int l15 = lane & 15;
    const int l4 = lane >> 4;

    // ---- stage x^T: phase A issue all 64 loads, phase B pack+write ----
    {
        const int c = lane;
        const float* xp = x + ((size_t)b * 256) * 514 + (size_t)h * 64 + c;
        float v[64];
        #pragma unroll
        for (int p = 0; p < 64; ++p)
            v[p] = xp[(size_t)(w * 64 + p) * 514];
        #pragma unroll
        for (int g = 0; g < 8; ++g) {
            uint4 pk;
            pk.x = pack2(v[g * 8 + 0], v[g * 8 + 1]);
            pk.y = pack2(v[g * 8 + 2], v[g * 8 + 3]);
            pk.z = pack2(v[g * 8 + 4], v[g * 8 + 5]);
            pk.w = pack2(v[g * 8 + 6], v[g * 8 + 7]);
            *(uint4*)&XT[c * MPAD + w * 64 + g * 8] = pk;
        }
    }
    __syncthreads();

    f32x4 acc[4][4];

    // ---- stage 1: S[c][o] = (XT @ Ws^T + bs)*gamma + beta ----
    #pragma unroll
    for (int mt = 0; mt < 4; ++mt)
        #pragma unroll
        for (int nt = 0; nt < 4; ++nt) acc[mt][nt] = 0.f;
    {
        const unsigned short* Wp = Wsb;
        bf16x8 bn1[4], bn2[4];
        #pragma unroll
        for (int nt = 0; nt < 4; ++nt) {
            bn1[nt] = *(const bf16x8*)(Wp + (size_t)(w * 64 + nt * 16 + l15) * 256 + 0 * 32 + l4 * 8);
            bn2[nt] = *(const bf16x8*)(Wp + (size_t)(w * 64 + nt * 16 + l15) * 256 + 1 * 32 + l4 * 8);
        }
        for (int kc = 0; kc < 8; ++kc) {
            bf16x8 bcur[4];
            #pragma unroll
            for (int nt = 0; nt < 4; ++nt) { bcur[nt] = bn1[nt]; bn1[nt] = bn2[nt]; }
            if (kc < 6) {
                #pragma unroll
                for (int nt = 0; nt < 4; ++nt)
                    bn2[nt] = *(const bf16x8*)(Wp + (size_t)(w * 64 + nt * 16 + l15) * 256 + (kc + 2) * 32 + l4 * 8);
            }
            #pragma unroll
            for (int mt = 0; mt < 4; ++mt) {
                bf16x8 afr = *(const bf16x8*)&XT[(mt * 16 + l15) * MPAD + kc * 32 + l4 * 8];
                #pragma unroll
                for (int nt = 0; nt < 4; ++nt)
                    acc[mt][nt] = __builtin_amdgcn_mfma_f32_16x16x32_bf16(afr, bcur[nt], acc[mt][nt], 0, 0, 0);
            }
        }
    }
    #pragma unroll
    for (int nt = 0; nt < 4; ++nt) {
        int o = w * 64 + nt * 16 + l15;
        float bsv = bs[o];
        float g = gb[(size_t)b * 512 + o];
        float be = gb[(size_t)b * 512 + 256 + o];
        #pragma unroll
        for (int mt = 0; mt < 4; ++mt)
            #pragma unroll
            for (int r = 0; r < 4; ++r) {
                int c = mt * 16 + l4 * 4 + r;
                S[c * MPAD + o] = f2bf((acc[mt][nt][r] + bsv) * g + be);
            }
    }
    __syncthreads();

    // ---- stage 2: S <- gelu(S @ HW1[h]^T + Hb1[h])  (in place) ----
    const unsigned short* W2p = HW1b + (size_t)h * 65536;
    #pragma unroll
    for (int mt = 0; mt < 4; ++mt)
        #pragma unroll
        for (int nt = 0; nt < 4; ++nt) acc[mt][nt] = 0.f;
    {
        bf16x8 bn1[4], bn2[4];
        #pragma unroll
        for (int nt = 0; nt < 4; ++nt) {
            bn1[nt] = *(const bf16x8*)(W2p + (size_t)(w * 64 + nt * 16 + l15) * 256 + 0 * 32 + l4 * 8);
            bn2[nt] = *(const bf16x8*)(W2p + (size_t)(w * 64 + nt * 16 + l15) * 256 + 1 * 32 + l4 * 8);
        }
        for (int kc = 0; kc < 8; ++kc) {
            bf16x8 bcur[4];
            #pragma unroll
            for (int nt = 0; nt < 4; ++nt) { bcur[nt] = bn1[nt]; bn1[nt] = bn2[nt]; }
            if (kc < 6) {
                #pragma unroll
                for (int nt = 0; nt < 4; ++nt)
                    bn2[nt] = *(const bf16x8*)(W2p + (size_t)(w * 64 + nt * 16 + l15) * 256 + (kc + 2) * 32 + l4 * 8);
            }
            #pragma unroll
            for (int mt = 0; mt < 4; ++mt) {
                bf16x8 afr = *(const bf16x8*)&S[(mt * 16 + l15) * MPAD + kc * 32 + l4 * 8];
                #pragma unroll
                for (int nt = 0; nt < 4; ++nt)
                    acc[mt][nt] = __builtin_amdgcn_mfma_f32_16x16x32_bf16(afr, bcur[nt], acc[mt][nt], 0, 0, 0);
            }
        }
    }
    __syncthreads();  // all S reads complete before in-place overwrite
    #pragma unroll
    for (int nt = 0; nt < 4; ++nt) {
        int kk = w * 64 + nt * 16 + l15;
        float hb = Hb1[(size_t)h * 256 + kk];
        #pragma unroll
        for (int mt = 0; mt < 4; ++mt)
            #pragma unroll
            for (int r = 0; r < 4; ++r) {
                int c = mt * 16 + l4 * 4 + r;
                S[c * MPAD + kk] = f2bf(gelu_fast(acc[mt][nt][r] + hb));
            }
    }
    __syncthreads();

    // ---- stage 3: acc = S(=T) @ HW2[h]^T ----
    const unsigned short* W3p = HW2b + (size_t)h * 65536;
    #pragma unroll
    for (int mt = 0; mt < 4; ++mt)
        #pragma unroll
        for (int nt = 0; nt < 4; ++nt) acc[mt][nt] = 0.f;
    {
        bf16x8 bn1[4], bn2[4];
        #pragma unroll
        for (int nt = 0; nt < 4; ++nt) {
            bn1[nt] = *(const bf16x8*)(W3p + (size_t)(w * 64 + nt * 16 + l15) * 256 + 0 * 32 + l4 * 8);
            bn2[nt] = *(const bf16x8*)(W3p + (size_t)(w * 64 + nt * 16 + l15) * 256 + 1 * 32 + l4 * 8);
        }
        for (int kc = 0; kc < 8; ++kc) {
            bf16x8 bcur[4];
            #pragma unroll
            for (int nt = 0; nt < 4; ++nt) { bcur[nt] = bn1[nt]; bn1[nt] = bn2[nt]; }
            if (kc < 6) {
                #pragma unroll
                for (int nt = 0; nt < 4; ++nt)
                    bn2[nt] = *(const bf16x8*)(W3p + (size_t)(w * 64 + nt * 16 + l15) * 256 + (kc + 2) * 32 + l4 * 8);
            }
            #pragma unroll
            for (int mt = 0; mt < 4; ++mt) {
                bf16x8 afr = *(const bf16x8*)&S[(mt * 16 + l15) * MPAD + kc * 32 + l4 * 8];
                #pragma unroll
                for (int nt = 0; nt < 4; ++nt)
                    acc[mt][nt] = __builtin_amdgcn_mfma_f32_16x16x32_bf16(afr, bcur[nt], acc[mt][nt], 0, 0, 0);
            }
        }
    }
    __syncthreads();  // all S reads complete before ST (alias) writes

    // ---- ST[p][c] = stage3 + Hb2 + residual (from pristine XT) ----
    #pragma unroll
    for (int nt = 0; nt < 4; ++nt) {
        int p = w * 64 + nt * 16 + l15;
        float hb = Hb2[(size_t)h * 256 + p];
        #pragma unroll
        for (int mt = 0; mt < 4; ++mt) {
            int c0 = mt * 16 + l4 * 4;
            ushort4 uv;
            uv.x = f2bf(acc[mt][nt][0] + hb + bf2f(XT[(c0 + 0) * MPAD + p]));
            uv.y = f2bf(acc[mt][nt][1] + hb + bf2f(XT[(c0 + 1) * MPAD + p]));
            uv.z = f2bf(acc[mt][nt][2] + hb + bf2f(XT[(c0 + 2) * MPAD + p]));
            uv.w = f2bf(acc[mt][nt][3] + hb + bf2f(XT[(c0 + 3) * MPAD + p]));
            *(ushort4*)(ST + p * 68 + c0) = uv;
        }
    }
    __syncthreads();

    // ---- coalesced copy-out: Xb only ----
    #pragma unroll
    for (int s = 0; s < 16; ++s) {
        int row = s * 16 + w * 4 + l4;
        ushort4 u = *(const ushort4*)(ST + row * 68 + l15 * 4);
        *(ushort4*)(Xb + ((size_t)(b * 256 + row)) * 512 + h * 64 + l15 * 4) = u;
    }
}

// ---------------------------------------------------------------------------
// GEMM v5 (m97 template): 128x128 tile, BK=64, 256 threads / 4 waves,
// single 32KB buffer, stage -> barrier -> compute -> barrier, ~3 blocks/CU.
// ---------------------------------------------------------------------------
DEV void stage_m97(const unsigned short* g, size_t gstride, int row0, int k0,
                   char* lbuf, int tid) {
    const int slot = tid & 7;
    const int r8 = (tid >> 3) & 7;
    const int wv = tid >> 6;
    const int swz = (slot ^ r8) * 16;
    #pragma unroll
    for (int i = 0; i < 4; ++i) {
        int chunk = i * 4 + wv;  // 0..15, wave-uniform
        int row = chunk * 8 + r8;
        const char* src = (const char*)(g + (size_t)(row0 + row) * gstride + k0) + swz;
        __builtin_amdgcn_global_load_lds((const glb_u32*)src,
                                         (lds_u32*)(lbuf + chunk * 1024), 16, 0, 0);
    }
}

DEV void gemm_loop97(const unsigned short* A, size_t sA,
                     const unsigned short* B, size_t sB,
                     int m0, int n0, int NT,
                     char* smem, int tid, f32x4 (&acc)[4][4]) {
    const int lane = tid & 63;
    const int w = tid >> 6;
    const int l15 = lane & 15, l4 = lane >> 4;
    const int wm = w >> 1, wn = w & 1;

    for (int t = 0; t < NT; ++t) {
        stage_m97(A, sA, m0, t * 64, smem, tid);
        stage_m97(B, sB, n0, t * 64, smem + 16384, tid);
        __syncthreads();  // compiler drains vmcnt before barrier
        #pragma unroll
        for (int kk = 0; kk < 2; ++kk) {
            bf16x8 af[4], bf[4];
            #pragma unroll
            for (int mf = 0; mf < 4; ++mf) {
                int row = wm * 64 + mf * 16 + l15;
                af[mf] = *(const bf16x8*)(smem + row * 128 + ((kk * 64 + l4 * 16) ^ ((row & 7) << 4)));
            }
            #pragma unroll
            for (int nf = 0; nf < 4; ++nf) {
                int row = wn * 64 + nf * 16 + l15;
                bf[nf] = *(const bf16x8*)(smem + 16384 + row * 128 + ((kk * 64 + l4 * 16) ^ ((row & 7) << 4)));
            }
            #pragma unroll
            for (int mf = 0; mf < 4; ++mf)
                #pragma unroll
                for (int nf = 0; nf < 4; ++nf)
                    acc[mf][nf] = __builtin_amdgcn_mfma_f32_16x16x32_bf16(
                        af[mf], bf[nf], acc[mf][nf], 0, 0, 0);
        }
        __syncthreads();  // reads done before next-tile staging overwrites
    }
}

// GEMM1: G = gelu(Xb @ FW1b^T + Fb1 + sc0*w512 + sc1*w513), LDS-bounce G store
__global__ __launch_bounds__(256, 3) void gemm1_kernel(
    const unsigned short* __restrict__ A,
    const unsigned short* __restrict__ B,
    const float* __restrict__ Fb1,
    const float* __restrict__ FW1,
    const float* __restrict__ scbuf,
    long pass_m0,
    unsigned short* __restrict__ G) {
    __shared__ __attribute__((aligned(16))) char smem[34816];

    const int nwg = gridDim.x;
    const int cpx = nwg >> 3;
    const int bid = (blockIdx.x & 7) * cpx + (blockIdx.x >> 3);
    const int m0 = (bid >> 4) * 128;
    const int n0 = (bid & 15) * 128;
    const int tid = threadIdx.x;
    const int lane = tid & 63;
    const int w = tid >> 6;
    const int l15 = lane & 15;
    const int l4 = lane >> 4;
    const int wm = w >> 1, wn = w & 1;

    f32x4 acc[4][4];
    #pragma unroll
    for (int mf = 0; mf < 4; ++mf)
        #pragma unroll
        for (int nf = 0; nf < 4; ++nf) acc[mf][nf] = 0.f;

    gemm_loop97(A, 512, B, 512, m0, n0, 8, smem, tid, acc);

    // epilogue: bias + sc + gelu -> bf16 into LT [128][136], then coalesced G store
    float fb[4], wa[4], wb[4];
    #pragma unroll
    for (int nf = 0; nf < 4; ++nf) {
        int n = n0 + wn * 64 + nf * 16 + l15;
        fb[nf] = Fb1[n];
        wa[nf] = FW1[(size_t)n * 514 + 512];
        wb[nf] = FW1[(size_t)n * 514 + 513];
    }
    f32x2 sc[4][4];
    #pragma unroll
    for (int mf = 0; mf < 4; ++mf)
        #pragma unroll
        for (int r = 0; r < 4; ++r) {
            long rowg = pass_m0 + m0 + wm * 64 + mf * 16 + l4 * 4 + r;
            sc[mf][r] = *(const f32x2*)(scbuf + rowg * 2);
        }
    unsigned short* LT = (unsigned short*)smem;  // [128][136]
    #pragma unroll
    for (int mf = 0; mf < 4; ++mf)
        #pragma unroll
        for (int nf = 0; nf < 4; ++nf)
            #pragma unroll
            for (int r = 0; r < 4; ++r) {
                float v = acc[mf][nf][r] + fb[nf] + sc[mf][r].x * wa[nf] + sc[mf][r].y * wb[nf];
                int rl = wm * 64 + mf * 16 + l4 * 4 + r;
                LT[rl * 136 + wn * 64 + nf * 16 + l15] = f2bf(gelu_fast(v));
            }
    __syncthreads();
    {
        const int lane16 = tid & 15, rowq = tid >> 4;
        #pragma unroll
        for (int s = 0; s < 8; ++s) {
            int row = s * 16 + rowq;
            uint4 d = *(const uint4*)((const char*)smem + row * 272 + lane16 * 16);
            *(uint4*)(G + ((size_t)(m0 + row)) * 2048 + n0 + lane16 * 8) = d;
        }
    }
}

// GEMM2: io[., 0..511] = G @ FW2b^T + Fb2 + bf2f(Xb)   (residual from Xb)
__global__ __launch_bounds__(256, 3) void gemm2_kernel(
    const unsigned short* __restrict__ A,
    const unsigned short* __restrict__ B,
    const float* __restrict__ Fb2,
    const unsigned short* __restrict__ Xb,
    long pass_m0,
    float* __restrict__ io) {
    __shared__ __attribute__((aligned(16))) char smem[32768];

    const int nwg = gridDim.x;
    const int cpx = nwg >> 3;
    const int bid = (blockIdx.x & 7) * cpx + (blockIdx.x >> 3);
    const int m0 = (bid >> 2) * 128;
    const int n0 = (bid & 3) * 128;
    const int tid = threadIdx.x;
    const int lane = tid & 63;
    const int w = tid >> 6;
    const int l15 = lane & 15;
    const int l4 = lane >> 4;
    const int wm = w >> 1, wn = w & 1;

    f32x4 acc[4][4];
    #pragma unroll
    for (int mf = 0; mf < 4; ++mf)
        #pragma unroll
        for (int nf = 0; nf < 4; ++nf) acc[mf][nf] = 0.f;

    gemm_loop97(A, 2048, B, 2048, m0, n0, 32, smem, tid, acc);

    #pragma unroll
    for (int nf = 0; nf < 4; ++nf) {
        int n = n0 + wn * 64 + nf * 16 + l15;
        float fbv = Fb2[n];
        #pragma unroll
        for (int mf = 0; mf < 4; ++mf)
            #pragma unroll
            for (int r = 0; r < 4; ++r) {
                long rowg = pass_m0 + m0 + wm * 64 + mf * 16 + l4 * 4 + r;
                float resv = bf2f(Xb[(size_t)rowg * 512 + n]);
                io[rowg * 514 + n] = acc[mf][nf][r] + fbv + resv;
            }
    }
}

// ---------------------------------------------------------------------------
extern "C" void kernel_launch(void* const* d_in, const int* in_sizes, int n_in,
                              void* d_out, int out_size, void* d_ws, size_t ws_size,
                              hipStream_t stream) {
    const float* x = (const float*)d_in[0];
    const float* Ws = (const float*)d_in[1];
    const float* bs = (const float*)d_in[2];
    const float* LW1 = (const float*)d_in[3];
    const float* Lb1 = (const float*)d_in[4];
    const float* LW2 = (const float*)d_in[5];
    const float* Lb2 = (const float*)d_in[6];
    const float* HW1 = (const float*)d_in[7];
    const float* Hb1 = (const float*)d_in[8];
    const float* HW2 = (const float*)d_in[9];
    const float* Hb2 = (const float*)d_in[10];
    const float* FW1 = (const float*)d_in[11];
    const float* Fb1 = (const float*)d_in[12];
    const float* FW2 = (const float*)d_in[13];
    const float* Fb2 = (const float*)d_in[14];
    float* out = (float*)d_out;

    char* ws = (char*)d_ws;
    unsigned short* Wsb = (unsigned short*)(ws);                 // 131072 B
    unsigned short* HW1b = (unsigned short*)(ws + 131072);       // 1048576 B
    unsigned short* HW2b = (unsigned short*)(ws + 1179648);      // 1048576 B
    unsigned short* FW1b = (unsigned short*)(ws + 2228224);      // 2097152 B
    unsigned short* FW2b = (unsigned short*)(ws + 4325376);      // 2097152 B
    float* gb = (float*)(ws + 6422528);                          // 524288 B
    float* scbuf = (float*)(ws + 6946816);                       // 524288 B
    unsigned short* Xb = (unsigned short*)(ws + 7471104);        // 67108864 B
    unsigned short* Gbuf = (unsigned short*)(ws + 7471104 + 67108864);

    const size_t fixed = 7471104 + 67108864;
    int npass = 32;
    for (int np = 2; np <= 32; np *= 2) {
        if (fixed + (size_t)268435456 / np <= ws_size) { npass = np; break; }
    }
    const long Mtot = 65536;
    const long Mp = Mtot / npass;

    cast_bf16_kernel<<<256, 256, 0, stream>>>(Ws, Wsb, 65536);
    cast_bf16_kernel<<<2048, 256, 0, stream>>>(HW1, HW1b, 524288);
    cast_bf16_kernel<<<2048, 256, 0, stream>>>(HW2, HW2b, 524288);
    cast_bf16_kernel<<<4096, 256, 0, stream>>>(FW2, FW2b, 1048576);
    cast_fw1_kernel<<<4096, 256, 0, stream>>>(FW1, FW1b);
    gb_kernel<<<32, 256, 0, stream>>>(x, LW1, Lb1, LW2, Lb2, gb);
    sc_copy_kernel<<<256, 256, 0, stream>>>(x, out, scbuf);

    mixer_kernel<<<2048, 256, 0, stream>>>(x, bs, Hb1, Hb2, Wsb, HW1b, HW2b, gb, Xb);

    for (int p = 0; p < npass; ++p) {
        long m0 = (long)p * Mp;
        gemm1_kernel<<<(int)(Mp / 128) * 16, 256, 0, stream>>>(
            Xb + m0 * 512, FW1b, Fb1, FW1, scbuf, m0, Gbuf);
        gemm2_kernel<<<(int)(Mp / 128) * 4, 256, 0, stream>>>(
            Gbuf, FW2b, Fb2, Xb, m0, out);
    }
}